// Round 1
// baseline (17040.503 us; speedup 1.0000x reference)
//
#include <hip/hip_runtime.h>
#include <hip/hip_cooperative_groups.h>
#include <math.h>

namespace cg = cooperative_groups;

// Dims
#define NB 32
#define ND 10
#define NBD 320
#define QL 16
#define DL 128
#define EMS 300
#define FS 300
#define HH 256
#define CC 50
#define NF 50
#define MF 20

__device__ __forceinline__ float sigmoidf_(float x) { return 1.0f / (1.0f + expf(-x)); }

// ---------------- transpose Wih [1024,300] -> WihT [300,1024] ----------------
__global__ void k_transpose_wih(const float* __restrict__ in, float* __restrict__ out)
{
    int idx = blockIdx.x * 256 + threadIdx.x; // 307200
    if (idx >= 300 * 1024) return;
    int j = idx & 1023, f = idx >> 10;
    out[idx] = in[j * 300 + f];
}

// ---------------- bias_comb[j] = proj_b @ WihT + bih + bhh ----------------
__global__ void k_bias(const float* __restrict__ WihT, const float* __restrict__ proj_b,
                       const float* __restrict__ bih, const float* __restrict__ bhh,
                       float* __restrict__ biasc)
{
    int j = blockIdx.x * 256 + threadIdx.x;
    if (j >= 1024) return;
    float s = bih[j] + bhh[j];
    for (int f = 0; f < 300; ++f) s += proj_b[f] * WihT[f * 1024 + j];
    biasc[j] = s;
}

// ---------------- generic tiled fp32 GEMM: C[M,N] = A[M,K] @ B[K,N] (+bias) ----------------
// GATHER: A row r is emb[gidx[r]]
template<bool GATHER>
__global__ __launch_bounds__(256)
void k_gemm(int M, int N, int K,
            const float* __restrict__ A, int lda,
            const int* __restrict__ gidx,
            const float* __restrict__ B, int ldb,
            const float* __restrict__ bias,
            float* __restrict__ C, int ldc)
{
    __shared__ float As[16][68];  // transposed: As[k][m]
    __shared__ float Bs[16][68];
    const int tid = threadIdx.x;
    const int row0 = blockIdx.y * 64;
    const int col0 = blockIdx.x * 64;
    const int tr = tid >> 4, tc = tid & 15;
    const int a_r = tid >> 2;
    const int a_k = (tid & 3) << 2;
    const int b_k = tid >> 4;
    const int b_c = (tid & 15) << 2;
    float acc[4][4] = {{0.f}};
    const float* arow = nullptr;
    if (row0 + a_r < M) {
        long r = row0 + a_r;
        arow = GATHER ? (A + (long)gidx[r] * lda) : (A + r * lda);
    }
    for (int k0 = 0; k0 < K; k0 += 16) {
        float4 av = make_float4(0.f, 0.f, 0.f, 0.f);
        if (arow) {
            int k = k0 + a_k;
            if (k + 4 <= K) av = *(const float4*)(arow + k);
            else {
                float t[4] = {0.f, 0.f, 0.f, 0.f};
                for (int i = 0; i < 4; ++i) if (k + i < K) t[i] = arow[k + i];
                av = make_float4(t[0], t[1], t[2], t[3]);
            }
        }
        As[a_k + 0][a_r] = av.x; As[a_k + 1][a_r] = av.y;
        As[a_k + 2][a_r] = av.z; As[a_k + 3][a_r] = av.w;
        float4 bv = make_float4(0.f, 0.f, 0.f, 0.f);
        {
            int kb = k0 + b_k;
            if (kb < K) {
                const float* brow = B + (long)kb * ldb + col0 + b_c;
                if (col0 + b_c + 4 <= N) bv = *(const float4*)brow;
                else {
                    float t[4] = {0.f, 0.f, 0.f, 0.f};
                    for (int j = 0; j < 4; ++j) if (col0 + b_c + j < N) t[j] = brow[j];
                    bv = make_float4(t[0], t[1], t[2], t[3]);
                }
            }
        }
        *(float4*)&Bs[b_k][b_c] = bv;
        __syncthreads();
        #pragma unroll
        for (int kk = 0; kk < 16; ++kk) {
            float4 a4 = *(const float4*)&As[kk][tr << 2];
            float4 b4 = *(const float4*)&Bs[kk][tc << 2];
            float a[4] = {a4.x, a4.y, a4.z, a4.w};
            float b[4] = {b4.x, b4.y, b4.z, b4.w};
            #pragma unroll
            for (int i = 0; i < 4; ++i)
                #pragma unroll
                for (int j = 0; j < 4; ++j)
                    acc[i][j] = fmaf(a[i], b[j], acc[i][j]);
        }
        __syncthreads();
    }
    #pragma unroll
    for (int i = 0; i < 4; ++i) {
        int r = row0 + (tr << 2) + i;
        if (r >= M) continue;
        #pragma unroll
        for (int j = 0; j < 4; ++j) {
            int cc = col0 + (tc << 2) + j;
            if (cc < N) C[(long)r * ldc + cc] = acc[i][j] + (bias ? bias[cc] : 0.f);
        }
    }
}

// ---------------- cooperative LSTM: 352 seqs (320 doc T=128, 32 query T=16) ----------------
// grid 352 blocks x 256 thr; block = (seq-tile 16) x (u-tile 16); thread = (s_local, u_local)
// computes all 4 gates for its (s,u); c lives in a register; h double-buffered in global.
__global__ __launch_bounds__(256)
void k_lstm(const float* __restrict__ xg_q, const float* __restrict__ xg_d,
            const float* __restrict__ Whh_q, const float* __restrict__ Whh_d,
            float* __restrict__ h_buf,
            float* __restrict__ enc_q, float* __restrict__ enc_d)
{
    __shared__ float hs[16][260];  // +4 pad: banks spread across s rows
    const int tid = threadIdx.x;
    const int st = blockIdx.x >> 4;   // 0..21 (20,21 = query tiles)
    const int ut = blockIdx.x & 15;
    const int s_l = tid >> 4, u_l = tid & 15;
    const int s = st * 16 + s_l;
    const bool is_q = (st >= 20);
    const int u = ut * 16 + u_l;
    const float* W = is_q ? Whh_q : Whh_d;
    const float* wi = W + (long)u * 256;   // gate rows: u, u+256, u+512, u+768
    float c_state = 0.f;
    const int HTOT = 352 * 256;
    cg::grid_group grid = cg::this_grid();

    for (int t = 0; t < 128; ++t) {
        const bool active = (!is_q) || (t < 16);
        if (t > 0 && active) {
            const float* hin = h_buf + ((t & 1) ^ 1) * HTOT + st * 16 * 256;
            #pragma unroll
            for (int i = 0; i < 4; ++i) {
                int f = i * 1024 + tid * 4;
                float4 v = *(const float4*)(hin + f);
                *(float4*)&hs[f >> 8][f & 255] = v;
            }
        }
        __syncthreads();
        if (active) {
            const float* xg = is_q ? (xg_q + ((long)(s - 320) * 16 + t) * 1024)
                                   : (xg_d + ((long)s * 128 + t) * 1024);
            float gi = xg[u], gf = xg[u + 256], gg = xg[u + 512], go = xg[u + 768];
            if (t > 0) {
                const float* hrow = hs[s_l];
                #pragma unroll 4
                for (int k = 0; k < 256; k += 4) {
                    float4 h4 = *(const float4*)(hrow + k);
                    float4 w0 = *(const float4*)(wi + k);
                    float4 w1 = *(const float4*)(wi + 65536 + k);
                    float4 w2 = *(const float4*)(wi + 131072 + k);
                    float4 w3 = *(const float4*)(wi + 196608 + k);
                    gi += h4.x * w0.x + h4.y * w0.y + h4.z * w0.z + h4.w * w0.w;
                    gf += h4.x * w1.x + h4.y * w1.y + h4.z * w1.z + h4.w * w1.w;
                    gg += h4.x * w2.x + h4.y * w2.y + h4.z * w2.z + h4.w * w2.w;
                    go += h4.x * w3.x + h4.y * w3.y + h4.z * w3.z + h4.w * w3.w;
                }
            }
            float ig = sigmoidf_(gi), fg = sigmoidf_(gf);
            float gc = tanhf(gg), og = sigmoidf_(go);
            c_state = fg * c_state + ig * gc;
            float hn = og * tanhf(c_state);
            h_buf[(t & 1) * HTOT + s * 256 + u] = hn;
            if (is_q) enc_q[((long)(s - 320) * 16 + t) * 256 + u] = hn;
            else      enc_d[((long)s * 128 + t) * 256 + u] = hn;
        }
        grid.sync();
    }
}

// ---------------- pd transpose: [40960,50] -> [320][50][128] ----------------
__global__ void k_pd_t(const float* __restrict__ pd, float* __restrict__ pdt)
{
    int idx = blockIdx.x * 256 + threadIdx.x;  // 2,048,000
    if (idx >= NBD * CC * DL) return;
    int d = idx & 127;
    int rest = idx >> 7;
    int c = rest % 50;
    int bd = rest / 50;
    pdt[idx] = pd[((long)bd * 128 + d) * 50 + c];
}

// ---------------- build conv input x [320][51][16][128] ----------------
__global__ __launch_bounds__(256)
void k_build_x(const float* __restrict__ pq, const float* __restrict__ pdt,
               const int* __restrict__ qtok, const int* __restrict__ dtok,
               const float* __restrict__ alpha, float* __restrict__ x)
{
    long idx = (long)blockIdx.x * 256 + threadIdx.x;
    const long TOT = (long)NBD * 51 * QL * DL;
    if (idx >= TOT) return;
    int d = (int)(idx & 127);
    long r1 = idx >> 7;
    int q = (int)(r1 & 15);
    long r2 = r1 >> 4;
    int c = (int)(r2 % 51);
    int bd = (int)(r2 / 51);
    int b = bd / 10;
    float v;
    if (c < 50) {
        v = pq[((long)b * 16 + q) * 50 + c] * pdt[((long)bd * 50 + c) * 128 + d];
    } else {
        v = (qtok[b * 16 + q] == dtok[bd * 128 + d]) ? alpha[0] : 0.f;
    }
    x[idx] = v;
}

// ---------------- fused conv(3x3,3x5,3x7)+relu+1x1+maxpool ----------------
// block = (dhalf, q, bd); 256 thr = 16 d-groups(x4) x 16 oc-slots.
#define XW 72
__global__ __launch_bounds__(256)
void k_conv(const float* __restrict__ x,
            const float* __restrict__ c1W, const float* __restrict__ c1b,
            const float* __restrict__ c2W, const float* __restrict__ c2b,
            const float* __restrict__ c3W, const float* __restrict__ c3b,
            const float* __restrict__ ccW, const float* __restrict__ ccb,
            float* __restrict__ pmax)
{
    __shared__ float smem[11016];  // 44064 B: xwin 3*51*72, later aliased by fbuf 150*68
    float* xwin = smem;
    float* fbuf = smem;
    const int tid = threadIdx.x;
    const int dh = blockIdx.x;
    const int q  = blockIdx.y;
    const int bd = blockIdx.z;

    for (int idx = tid; idx < 3 * 51 * 70; idx += 256) {
        int col = idx % 70;
        int rc  = idx / 70;
        int c   = rc % 51;
        int r3  = rc / 51;
        int qr  = q + r3 - 1;
        int dg  = dh * 64 + col - 3;
        float v = 0.f;
        if (qr >= 0 && qr < 16 && dg >= 0 && dg < 128)
            v = x[(((long)bd * 51 + c) * 16 + qr) * 128 + dg];
        xwin[rc * XW + col] = v;
    }
    __syncthreads();

    const int dgp = tid & 15;
    const int slot = tid >> 4;
    const int dl = dgp << 2;
    float acc[10][4];
    #pragma unroll
    for (int m = 0; m < 10; ++m) {
        int oc = slot + (m << 4);
        float bv = 0.f;
        if (oc < 50) bv = c1b[oc];
        else if (oc < 100) bv = c2b[oc - 50];
        else if (oc < 150) bv = c3b[oc - 100];
        acc[m][0] = acc[m][1] = acc[m][2] = acc[m][3] = bv;
    }

    for (int c = 0; c < 51; ++c) {
        #pragma unroll
        for (int r3 = 0; r3 < 3; ++r3) {
            const float* xrow = xwin + (r3 * 51 + c) * XW + dl;
            float4 w0 = *(const float4*)(xrow);
            float4 w1 = *(const float4*)(xrow + 4);
            float4 w2 = *(const float4*)(xrow + 8);
            float win[12] = {w0.x, w0.y, w0.z, w0.w, w1.x, w1.y, w1.z, w1.w,
                             w2.x, w2.y, w2.z, w2.w};
            #pragma unroll
            for (int m = 0; m < 10; ++m) {
                int oc = slot + (m << 4);
                if (oc < 50) {
                    const float* wp = c1W + ((oc * 51 + c) * 3 + r3) * 3;
                    #pragma unroll
                    for (int j = 0; j < 3; ++j) {
                        float wv = wp[j];
                        #pragma unroll
                        for (int i = 0; i < 4; ++i)
                            acc[m][i] = fmaf(win[i + 2 + j], wv, acc[m][i]);
                    }
                } else if (oc < 100) {
                    const float* wp = c2W + (((oc - 50) * 51 + c) * 3 + r3) * 5;
                    #pragma unroll
                    for (int j = 0; j < 5; ++j) {
                        float wv = wp[j];
                        #pragma unroll
                        for (int i = 0; i < 4; ++i)
                            acc[m][i] = fmaf(win[i + 1 + j], wv, acc[m][i]);
                    }
                } else if (oc < 150) {
                    const float* wp = c3W + (((oc - 100) * 51 + c) * 3 + r3) * 7;
                    #pragma unroll
                    for (int j = 0; j < 7; ++j) {
                        float wv = wp[j];
                        #pragma unroll
                        for (int i = 0; i < 4; ++i)
                            acc[m][i] = fmaf(win[i + j], wv, acc[m][i]);
                    }
                }
            }
        }
    }
    __syncthreads();   // all xwin reads complete before alias overwrite

    #pragma unroll
    for (int m = 0; m < 10; ++m) {
        int oc = slot + (m << 4);
        if (oc < 150) {
            float4 v = make_float4(fmaxf(acc[m][0], 0.f), fmaxf(acc[m][1], 0.f),
                                   fmaxf(acc[m][2], 0.f), fmaxf(acc[m][3], 0.f));
            *(float4*)&fbuf[oc * 68 + dl] = v;
        }
    }
    __syncthreads();

    // 1x1 conv over 150 ch + wave-max over 64 d positions
    const int d  = tid & 63;
    const int s2 = tid >> 6;  // wave id: uniform mf group per wave
    float f2[5];
    #pragma unroll
    for (int m2 = 0; m2 < 5; ++m2) f2[m2] = ccb[s2 * 5 + m2];
    for (int oc = 0; oc < 150; ++oc) {
        float fb = fbuf[oc * 68 + d];
        #pragma unroll
        for (int m2 = 0; m2 < 5; ++m2)
            f2[m2] = fmaf(fb, ccW[(s2 * 5 + m2) * 150 + oc], f2[m2]);
    }
    #pragma unroll
    for (int m2 = 0; m2 < 5; ++m2) {
        float v = f2[m2];
        for (int off = 32; off; off >>= 1) v = fmaxf(v, __shfl_xor(v, off));
        if ((tid & 63) == 0) {
            int mf = s2 * 5 + m2;
            pmax[((long)bd * 20 + mf) * 32 + q * 2 + dh] = v;
        }
    }
}

// ---------------- finalize: max over 32 partials, dot out_W, +out_b ----------------
__global__ void k_finalize(const float* __restrict__ pmax, const float* __restrict__ outW,
                           const float* __restrict__ outb, float* __restrict__ out)
{
    int bd = blockIdx.x;
    int t = threadIdx.x;  // 64
    float v = 0.f;
    if (t < 20) {
        const float* p = pmax + ((long)bd * 20 + t) * 32;
        float m = p[0];
        for (int i = 1; i < 32; ++i) m = fmaxf(m, p[i]);
        v = m * outW[t];
    }
    for (int off = 32; off; off >>= 1) v += __shfl_xor(v, off);
    if (t == 0) out[bd] = v + outb[0];
}

extern "C" void kernel_launch(void* const* d_in, const int* in_sizes, int n_in,
                              void* d_out, int out_size, void* d_ws, size_t ws_size,
                              hipStream_t stream)
{
    const int*   q_tok  = (const int*)d_in[0];
    const int*   d_tok  = (const int*)d_in[1];
    const float* emb    = (const float*)d_in[4];
    const float* proj_W = (const float*)d_in[5];
    const float* proj_b = (const float*)d_in[6];
    const float* q_Wih  = (const float*)d_in[7];
    const float* q_Whh  = (const float*)d_in[8];
    const float* q_bih  = (const float*)d_in[9];
    const float* q_bhh  = (const float*)d_in[10];
    const float* d_Wih  = (const float*)d_in[11];
    const float* d_Whh  = (const float*)d_in[12];
    const float* d_bih  = (const float*)d_in[13];
    const float* d_bhh  = (const float*)d_in[14];
    const float* qp_W   = (const float*)d_in[15];
    const float* qp_b   = (const float*)d_in[16];
    const float* dp_W   = (const float*)d_in[17];
    const float* dp_b   = (const float*)d_in[18];
    const float* alpha  = (const float*)d_in[19];
    const float* c1W = (const float*)d_in[20]; const float* c1b = (const float*)d_in[21];
    const float* c2W = (const float*)d_in[22]; const float* c2b = (const float*)d_in[23];
    const float* c3W = (const float*)d_in[24]; const float* c3b = (const float*)d_in[25];
    const float* ccW = (const float*)d_in[26]; const float* ccb = (const float*)d_in[27];
    const float* outW = (const float*)d_in[28]; const float* outb = (const float*)d_in[29];
    float* out = (float*)d_out;

    float* ws = (float*)d_ws;
    size_t o = 0;
    auto alloc = [&](size_t n) { float* p = ws + o; o += (n + 63) & ~(size_t)63; return p; };
    float* WihT_q = alloc(300 * 1024);
    float* WihT_d = alloc(300 * 1024);
    float* Wcq    = alloc(300 * 1024);
    float* Wcd    = alloc(300 * 1024);
    float* bq     = alloc(1024);
    float* bdv    = alloc(1024);
    float* h_buf  = alloc(2 * 352 * 256);
    float* enc_q  = alloc(512 * 256);
    float* pq     = alloc(512 * 50);
    float* pd     = alloc((size_t)40960 * 50);
    float* pdt    = alloc((size_t)40960 * 50);
    float* pmax   = alloc((size_t)320 * 20 * 32);
    float* enc_d  = alloc((size_t)40960 * 256);
    float* xg_q   = alloc((size_t)512 * 1024);
    float* xg_d   = alloc((size_t)40960 * 1024);
    float* x      = xg_d;  // alias: xg_d dead after LSTM; x needs 33.4M <= 41.9M floats

    // 1. transpose Wih
    k_transpose_wih<<<1200, 256, 0, stream>>>(q_Wih, WihT_q);
    k_transpose_wih<<<1200, 256, 0, stream>>>(d_Wih, WihT_d);
    // 2. W_comb = proj_W @ WihT
    k_gemm<false><<<dim3(16, 5), 256, 0, stream>>>(300, 1024, 300, proj_W, 300,
        (const int*)nullptr, WihT_q, 1024, (const float*)nullptr, Wcq, 1024);
    k_gemm<false><<<dim3(16, 5), 256, 0, stream>>>(300, 1024, 300, proj_W, 300,
        (const int*)nullptr, WihT_d, 1024, (const float*)nullptr, Wcd, 1024);
    // 3. bias_comb
    k_bias<<<4, 256, 0, stream>>>(WihT_q, proj_b, q_bih, q_bhh, bq);
    k_bias<<<4, 256, 0, stream>>>(WihT_d, proj_b, d_bih, d_bhh, bdv);
    // 4. xg = emb[tok] @ W_comb + bias_comb
    k_gemm<true><<<dim3(16, 8), 256, 0, stream>>>(512, 1024, 300, emb, 300,
        q_tok, Wcq, 1024, bq, xg_q, 1024);
    k_gemm<true><<<dim3(16, 640), 256, 0, stream>>>(40960, 1024, 300, emb, 300,
        d_tok, Wcd, 1024, bdv, xg_d, 1024);
    // 5. LSTMs (fused doc+query, cooperative, 1 grid sync per step)
    {
        void* args[] = {(void*)&xg_q, (void*)&xg_d, (void*)&q_Whh, (void*)&d_Whh,
                        (void*)&h_buf, (void*)&enc_q, (void*)&enc_d};
        hipLaunchCooperativeKernel((void*)k_lstm, dim3(352), dim3(256), args, 0, stream);
    }
    // 6. pq / pd projections
    k_gemm<false><<<dim3(1, 8), 256, 0, stream>>>(512, 50, 256, enc_q, 256,
        (const int*)nullptr, qp_W, 50, qp_b, pq, 50);
    k_gemm<false><<<dim3(1, 640), 256, 0, stream>>>(40960, 50, 256, enc_d, 256,
        (const int*)nullptr, dp_W, 50, dp_b, pd, 50);
    // 7. transpose pd for coalesced x build
    k_pd_t<<<8000, 256, 0, stream>>>(pd, pdt);
    // 8. build conv input (prod channels + exact-match channel)
    {
        long tot = (long)NBD * 51 * QL * DL;
        k_build_x<<<(int)((tot + 255) / 256), 256, 0, stream>>>(pq, pdt, q_tok, d_tok, alpha, x);
    }
    // 9. fused convs + relu + 1x1 + partial maxpool
    k_conv<<<dim3(2, 16, 320), 256, 0, stream>>>(x, c1W, c1b, c2W, c2b, c3W, c3b, ccW, ccb, pmax);
    // 10. finalize scores
    k_finalize<<<320, 64, 0, stream>>>(pmax, outW, outb, out);
}

// Round 2
// 10743.276 us; speedup vs baseline: 1.5862x; 1.5862x over previous
//
#include <hip/hip_runtime.h>
#include <hip/hip_cooperative_groups.h>
#include <math.h>

namespace cg = cooperative_groups;

// Dims
#define NB 32
#define ND 10
#define NBD 320
#define QL 16
#define DL 128
#define EMS 300
#define FS 300
#define HH 256
#define CC 50
#define NF 50
#define MF 20

__device__ __forceinline__ float sigmoidf_(float x) { return 1.0f / (1.0f + expf(-x)); }

// ---------------- transpose Wih [1024,300] -> WihT [300,1024] ----------------
__global__ void k_transpose_wih(const float* __restrict__ in, float* __restrict__ out)
{
    int idx = blockIdx.x * 256 + threadIdx.x; // 307200
    if (idx >= 300 * 1024) return;
    int j = idx & 1023, f = idx >> 10;
    out[idx] = in[j * 300 + f];
}

// ---------------- bias_comb[j] = proj_b @ WihT + bih + bhh ----------------
__global__ void k_bias(const float* __restrict__ WihT, const float* __restrict__ proj_b,
                       const float* __restrict__ bih, const float* __restrict__ bhh,
                       float* __restrict__ biasc)
{
    int j = blockIdx.x * 256 + threadIdx.x;
    if (j >= 1024) return;
    float s = bih[j] + bhh[j];
    for (int f = 0; f < 300; ++f) s += proj_b[f] * WihT[f * 1024 + j];
    biasc[j] = s;
}

// ---------------- generic tiled fp32 GEMM: C[M,N] = A[M,K] @ B[K,N] (+bias) ----------------
// GATHER: A row r is emb[gidx[r]]
template<bool GATHER>
__global__ __launch_bounds__(256)
void k_gemm(int M, int N, int K,
            const float* __restrict__ A, int lda,
            const int* __restrict__ gidx,
            const float* __restrict__ B, int ldb,
            const float* __restrict__ bias,
            float* __restrict__ C, int ldc)
{
    __shared__ float As[16][68];  // transposed: As[k][m]
    __shared__ float Bs[16][68];
    const int tid = threadIdx.x;
    const int row0 = blockIdx.y * 64;
    const int col0 = blockIdx.x * 64;
    const int tr = tid >> 4, tc = tid & 15;
    const int a_r = tid >> 2;
    const int a_k = (tid & 3) << 2;
    const int b_k = tid >> 4;
    const int b_c = (tid & 15) << 2;
    float acc[4][4] = {{0.f}};
    const float* arow = nullptr;
    if (row0 + a_r < M) {
        long r = row0 + a_r;
        arow = GATHER ? (A + (long)gidx[r] * lda) : (A + r * lda);
    }
    for (int k0 = 0; k0 < K; k0 += 16) {
        float4 av = make_float4(0.f, 0.f, 0.f, 0.f);
        if (arow) {
            int k = k0 + a_k;
            if (k + 4 <= K) av = *(const float4*)(arow + k);
            else {
                float t[4] = {0.f, 0.f, 0.f, 0.f};
                for (int i = 0; i < 4; ++i) if (k + i < K) t[i] = arow[k + i];
                av = make_float4(t[0], t[1], t[2], t[3]);
            }
        }
        As[a_k + 0][a_r] = av.x; As[a_k + 1][a_r] = av.y;
        As[a_k + 2][a_r] = av.z; As[a_k + 3][a_r] = av.w;
        float4 bv = make_float4(0.f, 0.f, 0.f, 0.f);
        {
            int kb = k0 + b_k;
            if (kb < K) {
                const float* brow = B + (long)kb * ldb + col0 + b_c;
                if (col0 + b_c + 4 <= N) bv = *(const float4*)brow;
                else {
                    float t[4] = {0.f, 0.f, 0.f, 0.f};
                    for (int j = 0; j < 4; ++j) if (col0 + b_c + j < N) t[j] = brow[j];
                    bv = make_float4(t[0], t[1], t[2], t[3]);
                }
            }
        }
        *(float4*)&Bs[b_k][b_c] = bv;
        __syncthreads();
        #pragma unroll
        for (int kk = 0; kk < 16; ++kk) {
            float4 a4 = *(const float4*)&As[kk][tr << 2];
            float4 b4 = *(const float4*)&Bs[kk][tc << 2];
            float a[4] = {a4.x, a4.y, a4.z, a4.w};
            float b[4] = {b4.x, b4.y, b4.z, b4.w};
            #pragma unroll
            for (int i = 0; i < 4; ++i)
                #pragma unroll
                for (int j = 0; j < 4; ++j)
                    acc[i][j] = fmaf(a[i], b[j], acc[i][j]);
        }
        __syncthreads();
    }
    #pragma unroll
    for (int i = 0; i < 4; ++i) {
        int r = row0 + (tr << 2) + i;
        if (r >= M) continue;
        #pragma unroll
        for (int j = 0; j < 4; ++j) {
            int cc = col0 + (tc << 2) + j;
            if (cc < N) C[(long)r * ldc + cc] = acc[i][j] + (bias ? bias[cc] : 0.f);
        }
    }
}

// ---------------- 64-wide register dot: hp[0..63] . w[0..15](float4) ----------------
__device__ __forceinline__ float dot64(const float* hp, const float4* w)
{
    float a0 = 0.f, a1 = 0.f, a2 = 0.f, a3 = 0.f;
    #pragma unroll
    for (int i = 0; i < 16; i += 4) {
        float4 h0 = *(const float4*)(hp + (i + 0) * 4);
        float4 h1 = *(const float4*)(hp + (i + 1) * 4);
        float4 h2 = *(const float4*)(hp + (i + 2) * 4);
        float4 h3 = *(const float4*)(hp + (i + 3) * 4);
        a0 = fmaf(h0.x, w[i+0].x, fmaf(h0.y, w[i+0].y, fmaf(h0.z, w[i+0].z, fmaf(h0.w, w[i+0].w, a0))));
        a1 = fmaf(h1.x, w[i+1].x, fmaf(h1.y, w[i+1].y, fmaf(h1.z, w[i+1].z, fmaf(h1.w, w[i+1].w, a1))));
        a2 = fmaf(h2.x, w[i+2].x, fmaf(h2.y, w[i+2].y, fmaf(h2.z, w[i+2].z, fmaf(h2.w, w[i+2].w, a2))));
        a3 = fmaf(h3.x, w[i+3].x, fmaf(h3.y, w[i+3].y, fmaf(h3.z, w[i+3].z, fmaf(h3.w, w[i+3].w, a3))));
    }
    return (a0 + a1) + (a2 + a3);
}

// ---------------- cooperative LSTM v2: register-resident weights ----------------
// Grid: 256 blocks = 16 u-tiles x 16 seq-tiles. Seq-tile: 20 doc seqs + 2 query seqs.
// Thread t: lr = t>>2 in [0,64) -> u_l = lr&15, gate g = lr>>4; q = t&3 (k-quarter).
// Per thread: 64 doc weights + 64 query weights live in VGPRs for all 128 steps.
// LDS h layout: hs[s][q*68 + k] (chunk offset 68 -> 4 distinct bank-quads, conflict-free).
__global__ __launch_bounds__(256)
void k_lstm2(const float* __restrict__ xg_q, const float* __restrict__ xg_d,
             const float* __restrict__ Whh_q, const float* __restrict__ Whh_d,
             float* __restrict__ h_buf,
             float* __restrict__ enc_q, float* __restrict__ enc_d)
{
    __shared__ float hs[22][272];
    __shared__ float dots[64][25];
    __shared__ float c_s[352];
    const int tid = threadIdx.x;
    const int ub = blockIdx.x & 15;
    const int st = blockIdx.x >> 4;
    const int lr = tid >> 2;
    const int q  = tid & 3;
    const int u_l = lr & 15;
    const int g   = lr >> 4;
    const int u   = ub * 16 + u_l;
    const int grow = g * 256 + u;

    float4 wd[16], wq[16];
    {
        const float* wsd = Whh_d + (long)grow * 256 + q * 64;
        const float* wsq = Whh_q + (long)grow * 256 + q * 64;
        #pragma unroll
        for (int i = 0; i < 16; ++i) {
            wd[i] = *(const float4*)(wsd + i * 4);
            wq[i] = *(const float4*)(wsq + i * 4);
        }
    }
    for (int i = tid; i < 352; i += 256) c_s[i] = 0.f;

    const int HTOT = 352 * 256;
    cg::grid_group grid = cg::this_grid();

    for (int t = 0; t < 128; ++t) {
        const int cur = t & 1, prev = cur ^ 1;
        if (t > 0) {
            const float* hb = h_buf + (long)prev * HTOT;
            for (int i = tid; i < 1408; i += 256) {        // 22 seqs x 64 float4
                int s  = i >> 6;
                int kk = (i & 63) * 4;
                int sg = (s < 20) ? (st * 20 + s) : (320 + st * 2 + (s - 20));
                float4 v = *(const float4*)(hb + (long)sg * 256 + kk);
                *(float4*)&hs[s][(kk >> 6) * 68 + (kk & 63)] = v;
            }
        }
        __syncthreads();
        if (t > 0) {
            for (int s = 0; s < 20; ++s) {
                float p = dot64(&hs[s][q * 68], wd);
                p += __shfl_xor(p, 1);
                p += __shfl_xor(p, 2);
                if (q == 0) dots[lr][s] = p;
            }
            if (t < 16) {
                #pragma unroll
                for (int s = 20; s < 22; ++s) {
                    float p = dot64(&hs[s][q * 68], wq);
                    p += __shfl_xor(p, 1);
                    p += __shfl_xor(p, 2);
                    if (q == 0) dots[lr][s] = p;
                }
            }
        }
        __syncthreads();
        for (int cu = tid; cu < 352; cu += 256) {
            int s = cu >> 4, ul2 = cu & 15;
            if (s >= 20 && t >= 16) continue;
            int sg = (s < 20) ? (st * 20 + s) : (320 + st * 2 + (s - 20));
            const float* xg = (s < 20)
                ? (xg_d + ((long)sg * 128 + t) * 1024)
                : (xg_q + ((long)(sg - 320) * 16 + t) * 1024);
            int uu = ub * 16 + ul2;
            float gi = xg[uu], gf = xg[uu + 256], gg = xg[uu + 512], go = xg[uu + 768];
            if (t > 0) {
                gi += dots[ul2][s];      gf += dots[16 + ul2][s];
                gg += dots[32 + ul2][s]; go += dots[48 + ul2][s];
            }
            float c = c_s[cu];
            float ig = sigmoidf_(gi), fg = sigmoidf_(gf);
            float gc = tanhf(gg), og = sigmoidf_(go);
            c = fg * c + ig * gc;
            c_s[cu] = c;
            float hn = og * tanhf(c);
            h_buf[(long)cur * HTOT + (long)sg * 256 + uu] = hn;
            if (s < 20) enc_d[((long)sg * 128 + t) * 256 + uu] = hn;
            else        enc_q[((long)(sg - 320) * 16 + t) * 256 + uu] = hn;
        }
        grid.sync();
    }
}

// ---------------- pd transpose: [40960,50] -> [320][50][128] ----------------
__global__ void k_pd_t(const float* __restrict__ pd, float* __restrict__ pdt)
{
    int idx = blockIdx.x * 256 + threadIdx.x;  // 2,048,000
    if (idx >= NBD * CC * DL) return;
    int d = idx & 127;
    int rest = idx >> 7;
    int c = rest % 50;
    int bd = rest / 50;
    pdt[idx] = pd[((long)bd * 128 + d) * 50 + c];
}

// ---------------- build conv input x [320][51][16][128] ----------------
__global__ __launch_bounds__(256)
void k_build_x(const float* __restrict__ pq, const float* __restrict__ pdt,
               const int* __restrict__ qtok, const int* __restrict__ dtok,
               const float* __restrict__ alpha, float* __restrict__ x)
{
    long idx = (long)blockIdx.x * 256 + threadIdx.x;
    const long TOT = (long)NBD * 51 * QL * DL;
    if (idx >= TOT) return;
    int d = (int)(idx & 127);
    long r1 = idx >> 7;
    int q = (int)(r1 & 15);
    long r2 = r1 >> 4;
    int c = (int)(r2 % 51);
    int bd = (int)(r2 / 51);
    int b = bd / 10;
    float v;
    if (c < 50) {
        v = pq[((long)b * 16 + q) * 50 + c] * pdt[((long)bd * 50 + c) * 128 + d];
    } else {
        v = (qtok[b * 16 + q] == dtok[bd * 128 + d]) ? alpha[0] : 0.f;
    }
    x[idx] = v;
}

// ---------------- fused conv(3x3,3x5,3x7)+relu+1x1+maxpool ----------------
// block = (dhalf, q, bd); 256 thr = 16 d-groups(x4) x 16 oc-slots.
#define XW 72
__global__ __launch_bounds__(256)
void k_conv(const float* __restrict__ x,
            const float* __restrict__ c1W, const float* __restrict__ c1b,
            const float* __restrict__ c2W, const float* __restrict__ c2b,
            const float* __restrict__ c3W, const float* __restrict__ c3b,
            const float* __restrict__ ccW, const float* __restrict__ ccb,
            float* __restrict__ pmax)
{
    __shared__ float smem[11016];  // 44064 B: xwin 3*51*72, later aliased by fbuf 150*68
    float* xwin = smem;
    float* fbuf = smem;
    const int tid = threadIdx.x;
    const int dh = blockIdx.x;
    const int q  = blockIdx.y;
    const int bd = blockIdx.z;

    for (int idx = tid; idx < 3 * 51 * 70; idx += 256) {
        int col = idx % 70;
        int rc  = idx / 70;
        int c   = rc % 51;
        int r3  = rc / 51;
        int qr  = q + r3 - 1;
        int dg  = dh * 64 + col - 3;
        float v = 0.f;
        if (qr >= 0 && qr < 16 && dg >= 0 && dg < 128)
            v = x[(((long)bd * 51 + c) * 16 + qr) * 128 + dg];
        xwin[rc * XW + col] = v;
    }
    __syncthreads();

    const int dgp = tid & 15;
    const int slot = tid >> 4;
    const int dl = dgp << 2;
    float acc[10][4];
    #pragma unroll
    for (int m = 0; m < 10; ++m) {
        int oc = slot + (m << 4);
        float bv = 0.f;
        if (oc < 50) bv = c1b[oc];
        else if (oc < 100) bv = c2b[oc - 50];
        else if (oc < 150) bv = c3b[oc - 100];
        acc[m][0] = acc[m][1] = acc[m][2] = acc[m][3] = bv;
    }

    for (int c = 0; c < 51; ++c) {
        #pragma unroll
        for (int r3 = 0; r3 < 3; ++r3) {
            const float* xrow = xwin + (r3 * 51 + c) * XW + dl;
            float4 w0 = *(const float4*)(xrow);
            float4 w1 = *(const float4*)(xrow + 4);
            float4 w2 = *(const float4*)(xrow + 8);
            float win[12] = {w0.x, w0.y, w0.z, w0.w, w1.x, w1.y, w1.z, w1.w,
                             w2.x, w2.y, w2.z, w2.w};
            #pragma unroll
            for (int m = 0; m < 10; ++m) {
                int oc = slot + (m << 4);
                if (oc < 50) {
                    const float* wp = c1W + ((oc * 51 + c) * 3 + r3) * 3;
                    #pragma unroll
                    for (int j = 0; j < 3; ++j) {
                        float wv = wp[j];
                        #pragma unroll
                        for (int i = 0; i < 4; ++i)
                            acc[m][i] = fmaf(win[i + 2 + j], wv, acc[m][i]);
                    }
                } else if (oc < 100) {
                    const float* wp = c2W + (((oc - 50) * 51 + c) * 3 + r3) * 5;
                    #pragma unroll
                    for (int j = 0; j < 5; ++j) {
                        float wv = wp[j];
                        #pragma unroll
                        for (int i = 0; i < 4; ++i)
                            acc[m][i] = fmaf(win[i + 1 + j], wv, acc[m][i]);
                    }
                } else if (oc < 150) {
                    const float* wp = c3W + (((oc - 100) * 51 + c) * 3 + r3) * 7;
                    #pragma unroll
                    for (int j = 0; j < 7; ++j) {
                        float wv = wp[j];
                        #pragma unroll
                        for (int i = 0; i < 4; ++i)
                            acc[m][i] = fmaf(win[i + j], wv, acc[m][i]);
                    }
                }
            }
        }
    }
    __syncthreads();   // all xwin reads complete before alias overwrite

    #pragma unroll
    for (int m = 0; m < 10; ++m) {
        int oc = slot + (m << 4);
        if (oc < 150) {
            float4 v = make_float4(fmaxf(acc[m][0], 0.f), fmaxf(acc[m][1], 0.f),
                                   fmaxf(acc[m][2], 0.f), fmaxf(acc[m][3], 0.f));
            *(float4*)&fbuf[oc * 68 + dl] = v;
        }
    }
    __syncthreads();

    // 1x1 conv over 150 ch + wave-max over 64 d positions
    const int d  = tid & 63;
    const int s2 = tid >> 6;  // wave id: uniform mf group per wave
    float f2[5];
    #pragma unroll
    for (int m2 = 0; m2 < 5; ++m2) f2[m2] = ccb[s2 * 5 + m2];
    for (int oc = 0; oc < 150; ++oc) {
        float fb = fbuf[oc * 68 + d];
        #pragma unroll
        for (int m2 = 0; m2 < 5; ++m2)
            f2[m2] = fmaf(fb, ccW[(s2 * 5 + m2) * 150 + oc], f2[m2]);
    }
    #pragma unroll
    for (int m2 = 0; m2 < 5; ++m2) {
        float v = f2[m2];
        for (int off = 32; off; off >>= 1) v = fmaxf(v, __shfl_xor(v, off));
        if ((tid & 63) == 0) {
            int mf = s2 * 5 + m2;
            pmax[((long)bd * 20 + mf) * 32 + q * 2 + dh] = v;
        }
    }
}

// ---------------- finalize: max over 32 partials, dot out_W, +out_b ----------------
__global__ void k_finalize(const float* __restrict__ pmax, const float* __restrict__ outW,
                           const float* __restrict__ outb, float* __restrict__ out)
{
    int bd = blockIdx.x;
    int t = threadIdx.x;  // 64
    float v = 0.f;
    if (t < 20) {
        const float* p = pmax + ((long)bd * 20 + t) * 32;
        float m = p[0];
        for (int i = 1; i < 32; ++i) m = fmaxf(m, p[i]);
        v = m * outW[t];
    }
    for (int off = 32; off; off >>= 1) v += __shfl_xor(v, off);
    if (t == 0) out[bd] = v + outb[0];
}

extern "C" void kernel_launch(void* const* d_in, const int* in_sizes, int n_in,
                              void* d_out, int out_size, void* d_ws, size_t ws_size,
                              hipStream_t stream)
{
    const int*   q_tok  = (const int*)d_in[0];
    const int*   d_tok  = (const int*)d_in[1];
    const float* emb    = (const float*)d_in[4];
    const float* proj_W = (const float*)d_in[5];
    const float* proj_b = (const float*)d_in[6];
    const float* q_Wih  = (const float*)d_in[7];
    const float* q_Whh  = (const float*)d_in[8];
    const float* q_bih  = (const float*)d_in[9];
    const float* q_bhh  = (const float*)d_in[10];
    const float* d_Wih  = (const float*)d_in[11];
    const float* d_Whh  = (const float*)d_in[12];
    const float* d_bih  = (const float*)d_in[13];
    const float* d_bhh  = (const float*)d_in[14];
    const float* qp_W   = (const float*)d_in[15];
    const float* qp_b   = (const float*)d_in[16];
    const float* dp_W   = (const float*)d_in[17];
    const float* dp_b   = (const float*)d_in[18];
    const float* alpha  = (const float*)d_in[19];
    const float* c1W = (const float*)d_in[20]; const float* c1b = (const float*)d_in[21];
    const float* c2W = (const float*)d_in[22]; const float* c2b = (const float*)d_in[23];
    const float* c3W = (const float*)d_in[24]; const float* c3b = (const float*)d_in[25];
    const float* ccW = (const float*)d_in[26]; const float* ccb = (const float*)d_in[27];
    const float* outW = (const float*)d_in[28]; const float* outb = (const float*)d_in[29];
    float* out = (float*)d_out;

    float* ws = (float*)d_ws;
    size_t o = 0;
    auto alloc = [&](size_t n) { float* p = ws + o; o += (n + 63) & ~(size_t)63; return p; };
    float* WihT_q = alloc(300 * 1024);
    float* WihT_d = alloc(300 * 1024);
    float* Wcq    = alloc(300 * 1024);
    float* Wcd    = alloc(300 * 1024);
    float* bq     = alloc(1024);
    float* bdv    = alloc(1024);
    float* h_buf  = alloc(2 * 352 * 256);
    float* enc_q  = alloc(512 * 256);
    float* pq     = alloc(512 * 50);
    float* pd     = alloc((size_t)40960 * 50);
    float* pdt    = alloc((size_t)40960 * 50);
    float* pmax   = alloc((size_t)320 * 20 * 32);
    float* enc_d  = alloc((size_t)40960 * 256);
    float* xg_q   = alloc((size_t)512 * 1024);
    float* xg_d   = alloc((size_t)40960 * 1024);
    float* x      = xg_d;  // alias: xg_d dead after LSTM; x needs 33.4M <= 41.9M floats

    // 1. transpose Wih
    k_transpose_wih<<<1200, 256, 0, stream>>>(q_Wih, WihT_q);
    k_transpose_wih<<<1200, 256, 0, stream>>>(d_Wih, WihT_d);
    // 2. W_comb = proj_W @ WihT
    k_gemm<false><<<dim3(16, 5), 256, 0, stream>>>(300, 1024, 300, proj_W, 300,
        (const int*)nullptr, WihT_q, 1024, (const float*)nullptr, Wcq, 1024);
    k_gemm<false><<<dim3(16, 5), 256, 0, stream>>>(300, 1024, 300, proj_W, 300,
        (const int*)nullptr, WihT_d, 1024, (const float*)nullptr, Wcd, 1024);
    // 3. bias_comb
    k_bias<<<4, 256, 0, stream>>>(WihT_q, proj_b, q_bih, q_bhh, bq);
    k_bias<<<4, 256, 0, stream>>>(WihT_d, proj_b, d_bih, d_bhh, bdv);
    // 4. xg = emb[tok] @ W_comb + bias_comb
    k_gemm<true><<<dim3(16, 8), 256, 0, stream>>>(512, 1024, 300, emb, 300,
        q_tok, Wcq, 1024, bq, xg_q, 1024);
    k_gemm<true><<<dim3(16, 640), 256, 0, stream>>>(40960, 1024, 300, emb, 300,
        d_tok, Wcd, 1024, bdv, xg_d, 1024);
    // 5. LSTMs (register-weight cooperative, 16 u-tiles x 16 seq-tiles)
    {
        void* args[] = {(void*)&xg_q, (void*)&xg_d, (void*)&q_Whh, (void*)&d_Whh,
                        (void*)&h_buf, (void*)&enc_q, (void*)&enc_d};
        hipLaunchCooperativeKernel((void*)k_lstm2, dim3(256), dim3(256), args, 0, stream);
    }
    // 6. pq / pd projections
    k_gemm<false><<<dim3(1, 8), 256, 0, stream>>>(512, 50, 256, enc_q, 256,
        (const int*)nullptr, qp_W, 50, qp_b, pq, 50);
    k_gemm<false><<<dim3(1, 640), 256, 0, stream>>>(40960, 50, 256, enc_d, 256,
        (const int*)nullptr, dp_W, 50, dp_b, pd, 50);
    // 7. transpose pd for coalesced x build
    k_pd_t<<<8000, 256, 0, stream>>>(pd, pdt);
    // 8. build conv input (prod channels + exact-match channel)
    {
        long tot = (long)NBD * 51 * QL * DL;
        k_build_x<<<(int)((tot + 255) / 256), 256, 0, stream>>>(pq, pdt, q_tok, d_tok, alpha, x);
    }
    // 9. fused convs + relu + 1x1 + partial maxpool
    k_conv<<<dim3(2, 16, 320), 256, 0, stream>>>(x, c1W, c1b, c2W, c2b, c3W, c3b, ccW, ccb, pmax);
    // 10. finalize scores
    k_finalize<<<320, 64, 0, stream>>>(pmax, outW, outb, out);
}

// Round 4
// 2069.931 us; speedup vs baseline: 8.2324x; 5.1902x over previous
//
#include <hip/hip_runtime.h>
#include <math.h>

// Dims
#define NB 32
#define ND 10
#define NBD 320
#define QL 16
#define DL 128
#define EMS 300
#define FS 300
#define HH 256
#define CC 50
#define NF 50
#define MF 20

typedef float f32x4 __attribute__((ext_vector_type(4)));
typedef _Float16 f16x8 __attribute__((ext_vector_type(8)));
typedef unsigned short us8 __attribute__((ext_vector_type(8)));

__device__ __forceinline__ float sigmoidf_(float x) { return 1.0f / (1.0f + expf(-x)); }
__device__ __forceinline__ float h2f(unsigned short v) {
    union { unsigned short u; _Float16 f; } c; c.u = v; return (float)c.f;
}
__device__ __forceinline__ unsigned short f2h(float x) {
    union { _Float16 f; unsigned short u; } c; c.f = (_Float16)x; return c.u;
}

// ---------------- transpose Wih [1024,300] -> WihT [300,1024] ----------------
__global__ void k_transpose_wih(const float* __restrict__ in, float* __restrict__ out)
{
    int idx = blockIdx.x * 256 + threadIdx.x;
    if (idx >= 300 * 1024) return;
    int j = idx & 1023, f = idx >> 10;
    out[idx] = in[j * 300 + f];
}

// ---------------- bias_comb[j] = proj_b @ WihT + bih + bhh ----------------
__global__ void k_bias(const float* __restrict__ WihT, const float* __restrict__ proj_b,
                       const float* __restrict__ bih, const float* __restrict__ bhh,
                       float* __restrict__ biasc)
{
    int j = blockIdx.x * 256 + threadIdx.x;
    if (j >= 1024) return;
    float s = bih[j] + bhh[j];
    for (int f = 0; f < 300; ++f) s += proj_b[f] * WihT[f * 1024 + j];
    biasc[j] = s;
}

// ---------------- generic tiled fp32 GEMM: C[M,N] = A[M,K] @ B[K,N] (+bias) ----------------
template<bool GATHER>
__global__ __launch_bounds__(256)
void k_gemm(int M, int N, int K,
            const float* __restrict__ A, int lda,
            const int* __restrict__ gidx,
            const float* __restrict__ B, int ldb,
            const float* __restrict__ bias,
            float* __restrict__ C, int ldc)
{
    __shared__ float As[16][68];
    __shared__ float Bs[16][68];
    const int tid = threadIdx.x;
    const int row0 = blockIdx.y * 64;
    const int col0 = blockIdx.x * 64;
    const int tr = tid >> 4, tc = tid & 15;
    const int a_r = tid >> 2;
    const int a_k = (tid & 3) << 2;
    const int b_k = tid >> 4;
    const int b_c = (tid & 15) << 2;
    float acc[4][4] = {{0.f}};
    const float* arow = nullptr;
    if (row0 + a_r < M) {
        long r = row0 + a_r;
        arow = GATHER ? (A + (long)gidx[r] * lda) : (A + r * lda);
    }
    for (int k0 = 0; k0 < K; k0 += 16) {
        float4 av = make_float4(0.f, 0.f, 0.f, 0.f);
        if (arow) {
            int k = k0 + a_k;
            if (k + 4 <= K) av = *(const float4*)(arow + k);
            else {
                float t[4] = {0.f, 0.f, 0.f, 0.f};
                for (int i = 0; i < 4; ++i) if (k + i < K) t[i] = arow[k + i];
                av = make_float4(t[0], t[1], t[2], t[3]);
            }
        }
        As[a_k + 0][a_r] = av.x; As[a_k + 1][a_r] = av.y;
        As[a_k + 2][a_r] = av.z; As[a_k + 3][a_r] = av.w;
        float4 bv = make_float4(0.f, 0.f, 0.f, 0.f);
        {
            int kb = k0 + b_k;
            if (kb < K) {
                const float* brow = B + (long)kb * ldb + col0 + b_c;
                if (col0 + b_c + 4 <= N) bv = *(const float4*)brow;
                else {
                    float t[4] = {0.f, 0.f, 0.f, 0.f};
                    for (int j = 0; j < 4; ++j) if (col0 + b_c + j < N) t[j] = brow[j];
                    bv = make_float4(t[0], t[1], t[2], t[3]);
                }
            }
        }
        *(float4*)&Bs[b_k][b_c] = bv;
        __syncthreads();
        #pragma unroll
        for (int kk = 0; kk < 16; ++kk) {
            float4 a4 = *(const float4*)&As[kk][tr << 2];
            float4 b4 = *(const float4*)&Bs[kk][tc << 2];
            float a[4] = {a4.x, a4.y, a4.z, a4.w};
            float b[4] = {b4.x, b4.y, b4.z, b4.w};
            #pragma unroll
            for (int i = 0; i < 4; ++i)
                #pragma unroll
                for (int j = 0; j < 4; ++j)
                    acc[i][j] = fmaf(a[i], b[j], acc[i][j]);
        }
        __syncthreads();
    }
    #pragma unroll
    for (int i = 0; i < 4; ++i) {
        int r = row0 + (tr << 2) + i;
        if (r >= M) continue;
        #pragma unroll
        for (int j = 0; j < 4; ++j) {
            int cc = col0 + (tc << 2) + j;
            if (cc < N) C[(long)r * ldc + cc] = acc[i][j] + (bias ? bias[cc] : 0.f);
        }
    }
}

// ---------------- pack Whh into gate-interleaved fp16 stream ----------------
// out ushort idx = kp*2048 + u*8 + e ; e = gate g + 4*kodd ; value = W[g*256+u][2kp+kodd]
__global__ void k_pack_whh(const float* __restrict__ W, unsigned short* __restrict__ out)
{
    int idx = blockIdx.x * 256 + threadIdx.x;   // 262144
    if (idx >= 262144) return;
    int e = idx & 7, u = (idx >> 3) & 255, kp = idx >> 11;
    int g = e & 3, ko = e >> 2;
    out[idx] = f2h(W[((long)g * 256 + u) * 256 + (kp * 2 + ko)]);
}

// ---------------- block-local LSTM: no grid sync; fp16 weight stream from L2 ----------------
// 176 blocks x 256 thr. Block owns 2 sequences; thread owns hidden unit u (4 gates, 2 seqs).
__global__ __launch_bounds__(256)
void k_lstm3(const float* __restrict__ xg_q, const float* __restrict__ xg_d,
             const us8* __restrict__ wpk_q, const us8* __restrict__ wpk_d,
             float* __restrict__ enc_q, float* __restrict__ enc_d)
{
    __shared__ float h0[256], h1[256];
    const int u = threadIdx.x;
    const int bid = blockIdx.x;
    const bool isq = bid >= 160;
    const int sg0 = isq ? (bid - 160) * 2 : bid * 2;
    const float* xg = isq ? xg_q : xg_d;
    const us8* wpk = isq ? wpk_q : wpk_d;
    float* enc = isq ? enc_q : enc_d;
    const int T = isq ? 16 : 128;
    float c0 = 0.f, c1 = 0.f;

    for (int t = 0; t < T; ++t) {
        const float* x0 = xg + ((long)(sg0 + 0) * T + t) * 1024;
        const float* x1 = xg + ((long)(sg0 + 1) * T + t) * 1024;
        float xi0 = x0[u], xf0 = x0[u + 256], xz0 = x0[u + 512], xo0 = x0[u + 768];
        float xi1 = x1[u], xf1 = x1[u + 256], xz1 = x1[u + 512], xo1 = x1[u + 768];
        float di0 = 0.f, df0 = 0.f, dz0 = 0.f, do0 = 0.f;
        float di1 = 0.f, df1 = 0.f, dz1 = 0.f, do1 = 0.f;
        if (t > 0) {
            #pragma unroll 8
            for (int kp = 0; kp < 128; ++kp) {
                us8 w = wpk[kp * 256 + u];
                float2 ha = *(const float2*)&h0[kp * 2];
                float2 hb = *(const float2*)&h1[kp * 2];
                float wi0 = h2f(w[0]), wf0 = h2f(w[1]), wz0 = h2f(w[2]), wo0 = h2f(w[3]);
                float wi1 = h2f(w[4]), wf1 = h2f(w[5]), wz1 = h2f(w[6]), wo1 = h2f(w[7]);
                di0 = fmaf(ha.x, wi0, fmaf(ha.y, wi1, di0));
                df0 = fmaf(ha.x, wf0, fmaf(ha.y, wf1, df0));
                dz0 = fmaf(ha.x, wz0, fmaf(ha.y, wz1, dz0));
                do0 = fmaf(ha.x, wo0, fmaf(ha.y, wo1, do0));
                di1 = fmaf(hb.x, wi0, fmaf(hb.y, wi1, di1));
                df1 = fmaf(hb.x, wf0, fmaf(hb.y, wf1, df1));
                dz1 = fmaf(hb.x, wz0, fmaf(hb.y, wz1, dz1));
                do1 = fmaf(hb.x, wo0, fmaf(hb.y, wo1, do1));
            }
        }
        __syncthreads();   // all h reads complete before overwrite
        {
            float ig = sigmoidf_(xi0 + di0), fg = sigmoidf_(xf0 + df0);
            float zg = tanhf(xz0 + dz0),     og = sigmoidf_(xo0 + do0);
            c0 = fg * c0 + ig * zg;
            float hn = og * tanhf(c0);
            h0[u] = hn;
            enc[((long)(sg0 + 0) * T + t) * 256 + u] = hn;
        }
        {
            float ig = sigmoidf_(xi1 + di1), fg = sigmoidf_(xf1 + df1);
            float zg = tanhf(xz1 + dz1),     og = sigmoidf_(xo1 + do1);
            c1 = fg * c1 + ig * zg;
            float hn = og * tanhf(c1);
            h1[u] = hn;
            enc[((long)(sg0 + 1) * T + t) * 256 + u] = hn;
        }
        __syncthreads();   // h writes visible before next step's reads
    }
}

// ---------------- build conv input xT fp16 [bd][q][d][64ic] ----------------
__global__ __launch_bounds__(256)
void k_build_xt(const float* __restrict__ pq, const float* __restrict__ pd,
                const int* __restrict__ qtok, const int* __restrict__ dtok,
                const float* __restrict__ alpha, unsigned short* __restrict__ xT)
{
    int p = blockIdx.x * 256 + threadIdx.x;
    if (p >= NBD * QL * DL) return;
    int d = p & 127, q = (p >> 7) & 15, bd = p >> 11;
    int b = bd / 10;
    const float* pqr = pq + ((long)b * 16 + q) * 50;
    const float* pdr = pd + ((long)bd * 128 + d) * 50;
    __attribute__((aligned(16))) unsigned short o[64];
    #pragma unroll
    for (int i = 0; i < 50; ++i) o[i] = f2h(pqr[i] * pdr[i]);
    o[50] = f2h(qtok[b * 16 + q] == dtok[bd * 128 + d] ? alpha[0] : 0.f);
    #pragma unroll
    for (int i = 51; i < 64; ++i) o[i] = 0;
    unsigned short* dst = xT + (long)p * 64;
    #pragma unroll
    for (int i = 0; i < 8; ++i) *(uint4*)(dst + i * 8) = *(const uint4*)(o + i * 8);
}

// ---------------- pack conv weights into swizzled A-fragment images ----------------
// Apk ushort idx = s*4096 + mtl*1024 + row*64 + ci*8 + e ; ic k = (ci^(row&7))*8+e
__global__ void k_pack_apk(const float* __restrict__ c1W, const float* __restrict__ c2W,
                           const float* __restrict__ c3W, unsigned short* __restrict__ Apk)
{
    int idx = blockIdx.x * 256 + threadIdx.x;
    if (idx >= 45 * 4096) return;
    int e = idx & 7, ci = (idx >> 3) & 7, row = (idx >> 6) & 15, mtl = (idx >> 10) & 3, s = idx >> 12;
    int k = ((ci ^ (row & 7)) << 3) + e;
    int ocl = mtl * 16 + row;
    float v = 0.f;
    if (ocl < 50 && k < 51) {
        if (s < 9)       { int sl = s;      v = c1W[((ocl * 51 + k) * 3 + sl / 3) * 3 + sl % 3]; }
        else if (s < 24) { int sl = s - 9;  v = c2W[((ocl * 51 + k) * 3 + sl / 5) * 5 + sl % 5]; }
        else             { int sl = s - 24; v = c3W[((ocl * 51 + k) * 3 + sl / 7) * 7 + sl % 7]; }
    }
    Apk[idx] = f2h(v);
}

// ---------------- pack 1x1 weights (transposed) + bias vector ----------------
__global__ void k_pack_cwb(const float* __restrict__ ccW,
                           const float* __restrict__ c1b, const float* __restrict__ c2b,
                           const float* __restrict__ c3b,
                           float* __restrict__ wccg, float* __restrict__ bvg)
{
    int idx = blockIdx.x * 256 + threadIdx.x;
    if (idx < 3840) {
        int oc = idx / 20, mf = idx % 20;
        int c = oc >> 6, ocl = oc & 63;
        wccg[idx] = (ocl < 50) ? ccW[mf * 150 + c * 50 + ocl] : 0.f;
    } else if (idx < 4032) {
        int oc = idx - 3840;
        int c = oc >> 6, ocl = oc & 63;
        const float* cb = (c == 0) ? c1b : (c == 1) ? c2b : c3b;
        bvg[oc] = (ocl < 50) ? cb[ocl] : 0.f;
    }
}

// ---------------- fused MFMA conv + relu + 1x1 + maxpool ----------------
// grid (8 d-eighths, 320 bd) x 512 thr (8 waves). M=192 oc (3 convs x 64 pad),
// N=256 (16q x 16d), K=64 per shift, 45 shifts. x window XOR-swizzled in LDS.
#define WROWS 396   // 18 q-rows x 22 d-cols
template<int MTB, int KW>
__device__ __forceinline__ void conv_shift(
    const unsigned short* xw, const unsigned short* ab,
    f32x4 (&acc)[12][2], int lane, int wv, int dq, int dd)
{
    const int row = lane & 15, j0 = lane >> 4;
    f16x8 af[4][2];
    #pragma unroll
    for (int m = 0; m < 4; ++m)
        #pragma unroll
        for (int ks = 0; ks < 2; ++ks)
            af[m][ks] = *(const f16x8*)&ab[m * 1024 + row * 64 + (((j0 + 4 * ks) ^ (row & 7)) << 3)];
    const int dco = dd - (KW >> 1) + 3;
    #pragma unroll
    for (int nt = 0; nt < 2; ++nt) {
        int p0 = wv * 32 + nt * 16;                       // n = p0 + col, col = row
        int pos = ((p0 >> 4) + dq) * 22 + row + dco;      // q = p0>>4, d = col
        f16x8 bf0 = *(const f16x8*)&xw[pos * 64 + ((j0 ^ (pos & 7)) << 3)];
        f16x8 bf1 = *(const f16x8*)&xw[pos * 64 + (((j0 + 4) ^ (pos & 7)) << 3)];
        #pragma unroll
        for (int m = 0; m < 4; ++m) {
            acc[MTB + m][nt] = __builtin_amdgcn_mfma_f32_16x16x32_f16(af[m][0], bf0, acc[MTB + m][nt], 0, 0, 0);
            acc[MTB + m][nt] = __builtin_amdgcn_mfma_f32_16x16x32_f16(af[m][1], bf1, acc[MTB + m][nt], 0, 0, 0);
        }
    }
}

__global__ __launch_bounds__(512)
void k_conv2(const unsigned short* __restrict__ xT, const unsigned short* __restrict__ Apk,
             const float* __restrict__ wccg, const float* __restrict__ bvg,
             float* __restrict__ pmax)
{
    // 58.9 KB LDS: x window (49.5 KB) + A image (8 KB); wcc aliased onto window post-loop
    __shared__ __align__(16) unsigned short smem_u[WROWS * 64 + 4096];
    __shared__ float bv_s[192];
    __shared__ float wmax_s[8 * 20];
    unsigned short* xw_u = smem_u;
    unsigned short* Ab_u = smem_u + WROWS * 64;
    float* wcc_s = (float*)smem_u;                        // valid only after conv loop
    const int tid = threadIdx.x, lane = tid & 63, wv = tid >> 6;
    const int dqt = blockIdx.x, bd = blockIdx.y;
    const int D0 = dqt * 16;

    // stage x window (zero-padded; swizzle baked into chunk slot)
    for (int i = tid; i < WROWS * 8; i += 512) {
        int row = i >> 3, ci = i & 7;
        int qa = row / 22 - 1, da = D0 - 3 + row % 22;
        int j = ci ^ (row & 7);
        uint4 v = make_uint4(0u, 0u, 0u, 0u);
        if (qa >= 0 && qa < 16 && da >= 0 && da < 128)
            v = *(const uint4*)&xT[((((long)bd * 16 + qa) * 128 + da) << 6) + j * 8];
        *(uint4*)&xw_u[row * 64 + ci * 8] = v;
    }
    if (tid < 192) bv_s[tid] = bvg[tid];

    uint4 areg = *(const uint4*)&Apk[tid * 8];            // prefetch shift 0
    f32x4 acc[12][2];
    #pragma unroll
    for (int mt = 0; mt < 12; ++mt) {
        acc[mt][0] = (f32x4)(0.f);
        acc[mt][1] = (f32x4)(0.f);
    }

    for (int s = 0; s < 45; ++s) {
        __syncthreads();                                  // staging done / prev A reads done
        *(uint4*)&Ab_u[tid * 8] = areg;
        if (s + 1 < 45) areg = *(const uint4*)&Apk[(s + 1) * 4096 + tid * 8];
        __syncthreads();                                  // A image visible
        if (s < 9)       { int sl = s;      conv_shift<0, 3>(xw_u, Ab_u, acc, lane, wv, sl / 3, sl % 3); }
        else if (s < 24) { int sl = s - 9;  conv_shift<4, 5>(xw_u, Ab_u, acc, lane, wv, sl / 5, sl % 5); }
        else             { int sl = s - 24; conv_shift<8, 7>(xw_u, Ab_u, acc, lane, wv, sl / 7, sl % 7); }
    }

    __syncthreads();                                      // conv reads done before alias overwrite
    for (int i = tid; i < 3840; i += 512) wcc_s[i] = wccg[i];

    // bias + relu in-register (oc row = mt*16 + (lane>>4)*4 + r)
    #pragma unroll
    for (int mt = 0; mt < 12; ++mt)
        #pragma unroll
        for (int r = 0; r < 4; ++r) {
            float b = bv_s[mt * 16 + ((lane >> 4) << 2) + r];
            acc[mt][0][r] = fmaxf(acc[mt][0][r] + b, 0.f);
            acc[mt][1][r] = fmaxf(acc[mt][1][r] + b, 0.f);
        }
    __syncthreads();                                      // wcc_s visible

    // 1x1: per-lane partial dot over its 48 oc rows; sum across the 4 row-groups
    // (lanes ^16,^32 share the same position column), then max over columns.
    #pragma unroll 4
    for (int mf = 0; mf < 20; ++mf) {
        float g0 = 0.f, g1 = 0.f;
        #pragma unroll
        for (int mt = 0; mt < 12; ++mt)
            #pragma unroll
            for (int r = 0; r < 4; ++r) {
                float w = wcc_s[(mt * 16 + ((lane >> 4) << 2) + r) * 20 + mf];
                g0 = fmaf(acc[mt][0][r], w, g0);
                g1 = fmaf(acc[mt][1][r], w, g1);
            }
        g0 += __shfl_xor(g0, 16); g0 += __shfl_xor(g0, 32);
        g1 += __shfl_xor(g1, 16); g1 += __shfl_xor(g1, 32);
        float gm = fmaxf(g0, g1);
        gm = fmaxf(gm, __shfl_xor(gm, 1));
        gm = fmaxf(gm, __shfl_xor(gm, 2));
        gm = fmaxf(gm, __shfl_xor(gm, 4));
        gm = fmaxf(gm, __shfl_xor(gm, 8));
        if (lane == 0) wmax_s[wv * 20 + mf] = gm;
    }
    __syncthreads();
    if (tid < 20) {
        float m = wmax_s[tid];
        #pragma unroll
        for (int w = 1; w < 8; ++w) m = fmaxf(m, wmax_s[w * 20 + tid]);
        pmax[((long)bd * 8 + dqt) * 20 + tid] = m;
    }
}

// ---------------- finalize: max over 8 d-eighths, +ccb, dot outW ----------------
__global__ void k_finalize(const float* __restrict__ pmax, const float* __restrict__ ccb,
                           const float* __restrict__ outW, const float* __restrict__ outb,
                           float* __restrict__ out)
{
    int bd = blockIdx.x;
    int t = threadIdx.x;  // 64
    float v = 0.f;
    if (t < 20) {
        const float* p = pmax + (long)bd * 160;
        float m = p[t];
        #pragma unroll
        for (int i = 1; i < 8; ++i) m = fmaxf(m, p[i * 20 + t]);
        v = (m + ccb[t]) * outW[t];   // max commutes with +const (ccb folded post-pool)
    }
    for (int off = 32; off; off >>= 1) v += __shfl_xor(v, off);
    if (t == 0) out[bd] = v + outb[0];
}

extern "C" void kernel_launch(void* const* d_in, const int* in_sizes, int n_in,
                              void* d_out, int out_size, void* d_ws, size_t ws_size,
                              hipStream_t stream)
{
    const int*   q_tok  = (const int*)d_in[0];
    const int*   d_tok  = (const int*)d_in[1];
    const float* emb    = (const float*)d_in[4];
    const float* proj_W = (const float*)d_in[5];
    const float* proj_b = (const float*)d_in[6];
    const float* q_Wih  = (const float*)d_in[7];
    const float* q_Whh  = (const float*)d_in[8];
    const float* q_bih  = (const float*)d_in[9];
    const float* q_bhh  = (const float*)d_in[10];
    const float* d_Wih  = (const float*)d_in[11];
    const float* d_Whh  = (const float*)d_in[12];
    const float* d_bih  = (const float*)d_in[13];
    const float* d_bhh  = (const float*)d_in[14];
    const float* qp_W   = (const float*)d_in[15];
    const float* qp_b   = (const float*)d_in[16];
    const float* dp_W   = (const float*)d_in[17];
    const float* dp_b   = (const float*)d_in[18];
    const float* alpha  = (const float*)d_in[19];
    const float* c1W = (const float*)d_in[20]; const float* c1b = (const float*)d_in[21];
    const float* c2W = (const float*)d_in[22]; const float* c2b = (const float*)d_in[23];
    const float* c3W = (const float*)d_in[24]; const float* c3b = (const float*)d_in[25];
    const float* ccW = (const float*)d_in[26]; const float* ccb = (const float*)d_in[27];
    const float* outW = (const float*)d_in[28]; const float* outb = (const float*)d_in[29];
    float* out = (float*)d_out;

    float* ws = (float*)d_ws;
    size_t o = 0;
    auto alloc = [&](size_t n) { float* p = ws + o; o += (n + 63) & ~(size_t)63; return p; };
    float* WihT_q = alloc(300 * 1024);
    float* WihT_d = alloc(300 * 1024);
    float* Wcq    = alloc(300 * 1024);
    float* Wcd    = alloc(300 * 1024);
    float* bq     = alloc(1024);
    float* bdv    = alloc(1024);
    unsigned short* wpkq = (unsigned short*)alloc(131072);   // 262144 fp16
    unsigned short* wpkd = (unsigned short*)alloc(131072);
    float* enc_q  = alloc(512 * 256);
    float* pq     = alloc(512 * 50);
    float* pd     = alloc((size_t)40960 * 50);
    unsigned short* Apk  = (unsigned short*)alloc(92160);    // 184320 fp16
    float* wccg   = alloc(3840);
    float* bvg    = alloc(192);
    float* pmax   = alloc((size_t)320 * 8 * 20);
    float* enc_d  = alloc((size_t)40960 * 256);
    float* xg_q   = alloc((size_t)512 * 1024);
    float* xg_d   = alloc((size_t)40960 * 1024);
    unsigned short* xT = (unsigned short*)xg_d;  // alias: xg_d dead after LSTM

    // 1. transpose Wih
    k_transpose_wih<<<1200, 256, 0, stream>>>(q_Wih, WihT_q);
    k_transpose_wih<<<1200, 256, 0, stream>>>(d_Wih, WihT_d);
    // 2. W_comb = proj_W @ WihT
    k_gemm<false><<<dim3(16, 5), 256, 0, stream>>>(300, 1024, 300, proj_W, 300,
        (const int*)nullptr, WihT_q, 1024, (const float*)nullptr, Wcq, 1024);
    k_gemm<false><<<dim3(16, 5), 256, 0, stream>>>(300, 1024, 300, proj_W, 300,
        (const int*)nullptr, WihT_d, 1024, (const float*)nullptr, Wcd, 1024);
    // 3. bias_comb
    k_bias<<<4, 256, 0, stream>>>(WihT_q, proj_b, q_bih, q_bhh, bq);
    k_bias<<<4, 256, 0, stream>>>(WihT_d, proj_b, d_bih, d_bhh, bdv);
    // 4. pack LSTM weights fp16 gate-interleaved
    k_pack_whh<<<1024, 256, 0, stream>>>(q_Whh, wpkq);
    k_pack_whh<<<1024, 256, 0, stream>>>(d_Whh, wpkd);
    // 5. pack conv weights (swizzled MFMA images) + 1x1/bias packs
    k_pack_apk<<<720, 256, 0, stream>>>(c1W, c2W, c3W, Apk);
    k_pack_cwb<<<16, 256, 0, stream>>>(ccW, c1b, c2b, c3b, wccg, bvg);
    // 6. xg = emb[tok] @ W_comb + bias_comb
    k_gemm<true><<<dim3(16, 8), 256, 0, stream>>>(512, 1024, 300, emb, 300,
        q_tok, Wcq, 1024, bq, xg_q, 1024);
    k_gemm<true><<<dim3(16, 640), 256, 0, stream>>>(40960, 1024, 300, emb, 300,
        d_tok, Wcd, 1024, bdv, xg_d, 1024);
    // 7. LSTMs: block-local, no grid sync
    k_lstm3<<<176, 256, 0, stream>>>(xg_q, xg_d, (const us8*)wpkq, (const us8*)wpkd,
                                     enc_q, enc_d);
    // 8. pq / pd projections
    k_gemm<false><<<dim3(1, 8), 256, 0, stream>>>(512, 50, 256, enc_q, 256,
        (const int*)nullptr, qp_W, 50, qp_b, pq, 50);
    k_gemm<false><<<dim3(1, 640), 256, 0, stream>>>(40960, 50, 256, enc_d, 256,
        (const int*)nullptr, dp_W, 50, dp_b, pd, 50);
    // 9. build fp16 conv input (ic-contiguous, FULL 64-ushort rows)
    k_build_xt<<<2560, 256, 0, stream>>>(pq, pd, q_tok, d_tok, alpha, xT);
    // 10. fused MFMA convs + relu + 1x1 + maxpool partials
    k_conv2<<<dim3(8, 320), 512, 0, stream>>>(xT, Apk, wccg, bvg, pmax);
    // 11. finalize scores
    k_finalize<<<320, 64, 0, stream>>>(pmax, ccb, outW, outb, out);
}

// Round 5
// 1490.442 us; speedup vs baseline: 11.4332x; 1.3888x over previous
//
#include <hip/hip_runtime.h>
#include <math.h>

// Dims
#define NB 32
#define ND 10
#define NBD 320
#define QL 16
#define DL 128
#define HH 256
#define CC 50
#define MF 20

typedef float f32x4 __attribute__((ext_vector_type(4)));
typedef _Float16 f16x8 __attribute__((ext_vector_type(8)));
typedef _Float16 h2t __attribute__((ext_vector_type(2)));

#if defined(__has_builtin)
#if __has_builtin(__builtin_amdgcn_fdot2)
#define HAVE_FDOT2 1
#endif
#endif

__device__ __forceinline__ float sigmoidf_(float x) { return 1.0f / (1.0f + expf(-x)); }
__device__ __forceinline__ unsigned short f2h(float x) {
    union { _Float16 f; unsigned short u; } c; c.f = (_Float16)x; return c.u;
}
__device__ __forceinline__ h2t u2h(unsigned int v) {
    union { unsigned int u; h2t h; } c; c.u = v; return c.h;
}
__device__ __forceinline__ float fdot2_(h2t a, h2t b, float c) {
#ifdef HAVE_FDOT2
    return __builtin_amdgcn_fdot2(a, b, c, false);
#else
    return c + (float)a[0] * (float)b[0] + (float)a[1] * (float)b[1];
#endif
}

// ---------------- transpose Wih [1024,300] -> WihT [300,1024] ----------------
__global__ void k_transpose_wih(const float* __restrict__ in, float* __restrict__ out)
{
    int idx = blockIdx.x * 256 + threadIdx.x;
    if (idx >= 300 * 1024) return;
    int j = idx & 1023, f = idx >> 10;
    out[idx] = in[j * 300 + f];
}

// ---------------- bias_comb[j] = proj_b @ WihT + bih + bhh ----------------
__global__ void k_bias(const float* __restrict__ WihT, const float* __restrict__ proj_b,
                       const float* __restrict__ bih, const float* __restrict__ bhh,
                       float* __restrict__ biasc)
{
    int j = blockIdx.x * 256 + threadIdx.x;
    if (j >= 1024) return;
    float s = bih[j] + bhh[j];
    for (int f = 0; f < 300; ++f) s += proj_b[f] * WihT[f * 1024 + j];
    biasc[j] = s;
}

// ---------------- generic tiled fp32 GEMM: C[M,N] = A[M,K] @ B[K,N] (+bias) ----------------
template<bool GATHER>
__global__ __launch_bounds__(256)
void k_gemm(int M, int N, int K,
            const float* __restrict__ A, int lda,
            const int* __restrict__ gidx,
            const float* __restrict__ B, int ldb,
            const float* __restrict__ bias,
            float* __restrict__ C, int ldc)
{
    __shared__ float As[16][68];
    __shared__ float Bs[16][68];
    const int tid = threadIdx.x;
    const int row0 = blockIdx.y * 64;
    const int col0 = blockIdx.x * 64;
    const int tr = tid >> 4, tc = tid & 15;
    const int a_r = tid >> 2;
    const int a_k = (tid & 3) << 2;
    const int b_k = tid >> 4;
    const int b_c = (tid & 15) << 2;
    float acc[4][4] = {{0.f}};
    const float* arow = nullptr;
    if (row0 + a_r < M) {
        long r = row0 + a_r;
        arow = GATHER ? (A + (long)gidx[r] * lda) : (A + r * lda);
    }
    for (int k0 = 0; k0 < K; k0 += 16) {
        float4 av = make_float4(0.f, 0.f, 0.f, 0.f);
        if (arow) {
            int k = k0 + a_k;
            if (k + 4 <= K) av = *(const float4*)(arow + k);
            else {
                float t[4] = {0.f, 0.f, 0.f, 0.f};
                for (int i = 0; i < 4; ++i) if (k + i < K) t[i] = arow[k + i];
                av = make_float4(t[0], t[1], t[2], t[3]);
            }
        }
        As[a_k + 0][a_r] = av.x; As[a_k + 1][a_r] = av.y;
        As[a_k + 2][a_r] = av.z; As[a_k + 3][a_r] = av.w;
        float4 bv = make_float4(0.f, 0.f, 0.f, 0.f);
        {
            int kb = k0 + b_k;
            if (kb < K) {
                const float* brow = B + (long)kb * ldb + col0 + b_c;
                if (col0 + b_c + 4 <= N) bv = *(const float4*)brow;
                else {
                    float t[4] = {0.f, 0.f, 0.f, 0.f};
                    for (int j = 0; j < 4; ++j) if (col0 + b_c + j < N) t[j] = brow[j];
                    bv = make_float4(t[0], t[1], t[2], t[3]);
                }
            }
        }
        *(float4*)&Bs[b_k][b_c] = bv;
        __syncthreads();
        #pragma unroll
        for (int kk = 0; kk < 16; ++kk) {
            float4 a4 = *(const float4*)&As[kk][tr << 2];
            float4 b4 = *(const float4*)&Bs[kk][tc << 2];
            float a[4] = {a4.x, a4.y, a4.z, a4.w};
            float b[4] = {b4.x, b4.y, b4.z, b4.w};
            #pragma unroll
            for (int i = 0; i < 4; ++i)
                #pragma unroll
                for (int j = 0; j < 4; ++j)
                    acc[i][j] = fmaf(a[i], b[j], acc[i][j]);
        }
        __syncthreads();
    }
    #pragma unroll
    for (int i = 0; i < 4; ++i) {
        int r = row0 + (tr << 2) + i;
        if (r >= M) continue;
        #pragma unroll
        for (int j = 0; j < 4; ++j) {
            int cc = col0 + (tc << 2) + j;
            if (cc < N) C[(long)r * ldc + cc] = acc[i][j] + (bias ? bias[cc] : 0.f);
        }
    }
}

// ---------------- pack Whh: dword idx = ((kh*64+kp)*256+u)*4+g = half2(W[g*256+u][K],[K+1]) ----------------
// K = kh*128 + kp*2
__global__ void k_pack_whh4(const float* __restrict__ W, unsigned int* __restrict__ out)
{
    int idx = blockIdx.x * 256 + threadIdx.x;   // 131072 dwords
    if (idx >= 131072) return;
    int g = idx & 3, u = (idx >> 2) & 255, kp = (idx >> 10) & 63, kh = idx >> 16;
    int K = kh * 128 + kp * 2;
    const float* wr = W + ((long)g * 256 + u) * 256 + K;
    union { struct { _Float16 lo, hi; } h; unsigned int u32; } c;
    c.h.lo = (_Float16)wr[0]; c.h.hi = (_Float16)wr[1];
    out[idx] = c.u32;
}

// ---------------- pack emb -> fp16 [50000][320] (zero-pad cols 300..319) ----------------
__global__ void k_pack_emb16(const float* __restrict__ emb, unsigned short* __restrict__ out)
{
    int idx = blockIdx.x * 256 + threadIdx.x;
    if (idx >= 50000 * 320) return;
    int e = idx % 320, v = idx / 320;
    out[idx] = f2h(e < 300 ? emb[(long)v * 300 + e] : 0.f);
}

// ---------------- pack Wc [300][1024] fp32 -> WcT fp16 [1024][320] ----------------
__global__ void k_pack_wct16(const float* __restrict__ Wc, unsigned short* __restrict__ out)
{
    int idx = blockIdx.x * 256 + threadIdx.x;
    if (idx >= 1024 * 320) return;
    int k = idx % 320, n = idx / 320;
    out[idx] = f2h(k < 300 ? Wc[(long)k * 1024 + n] : 0.f);
}

// ---------------- MFMA fp16 gather-GEMM: C[M,1024] = A16[gidx[r]][320] @ BtT + bias ----------------
// tile M=64 x N=128, K=320 (10 steps of 32). 256 thr = 4 waves; wave owns 32 cols.
template<bool GATHER>
__global__ __launch_bounds__(256)
void k_gemm16(const unsigned short* __restrict__ A16, const int* __restrict__ gidx,
              const unsigned short* __restrict__ Bt, const float* __restrict__ bias,
              float* __restrict__ C)
{
    __shared__ __align__(16) unsigned short Al[64 * 32];
    __shared__ __align__(16) unsigned short Bl[128 * 32];
    const int tid = threadIdx.x, lane = tid & 63, wv = tid >> 6;
    const int row0 = blockIdx.y * 64, col0 = blockIdx.x * 128;
    const int ar = tid >> 2, ac = tid & 3;
    const unsigned short* arow;
    {
        long r = row0 + ar;
        arow = A16 + (GATHER ? (long)gidx[r] : r) * 320;
    }
    const int bn0 = tid >> 2;            // B stage: 2 chunk-loads/thread
    const int bc0 = tid & 3;
    f32x4 acc[4][2];
    #pragma unroll
    for (int m = 0; m < 4; ++m) { acc[m][0] = (f32x4)(0.f); acc[m][1] = (f32x4)(0.f); }
    const int r_frag = lane & 15, j0 = lane >> 4;

    for (int kt = 0; kt < 10; ++kt) {
        const int k0 = kt * 32;
        uint4 av = *(const uint4*)(arow + k0 + ac * 8);
        uint4 bv0 = *(const uint4*)(Bt + (long)(col0 + bn0) * 320 + k0 + bc0 * 8);
        uint4 bv1 = *(const uint4*)(Bt + (long)(col0 + 64 + bn0) * 320 + k0 + bc0 * 8);
        __syncthreads();   // prior frag reads done
        *(uint4*)&Al[ar * 32 + ((ac ^ ((ar >> 1) & 3)) << 3)] = av;
        *(uint4*)&Bl[bn0 * 32 + ((bc0 ^ ((bn0 >> 1) & 3)) << 3)] = bv0;
        *(uint4*)&Bl[(64 + bn0) * 32 + ((bc0 ^ (((64 + bn0) >> 1) & 3)) << 3)] = bv1;
        __syncthreads();   // tiles visible
        f16x8 a[4], b[2];
        #pragma unroll
        for (int m = 0; m < 4; ++m) {
            int rr = m * 16 + r_frag;
            a[m] = *(const f16x8*)&Al[rr * 32 + ((j0 ^ ((rr >> 1) & 3)) << 3)];
        }
        #pragma unroll
        for (int n2 = 0; n2 < 2; ++n2) {
            int nn = wv * 32 + n2 * 16 + r_frag;
            b[n2] = *(const f16x8*)&Bl[nn * 32 + ((j0 ^ ((nn >> 1) & 3)) << 3)];
        }
        #pragma unroll
        for (int m = 0; m < 4; ++m)
            #pragma unroll
            for (int n2 = 0; n2 < 2; ++n2)
                acc[m][n2] = __builtin_amdgcn_mfma_f32_16x16x32_f16(a[m], b[n2], acc[m][n2], 0, 0, 0);
    }
    #pragma unroll
    for (int m = 0; m < 4; ++m)
        #pragma unroll
        for (int n2 = 0; n2 < 2; ++n2) {
            int cc = col0 + wv * 32 + n2 * 16 + r_frag;
            float bs = bias[cc];
            #pragma unroll
            for (int r = 0; r < 4; ++r) {
                int rr = row0 + m * 16 + j0 * 4 + r;
                C[(long)rr * 1024 + cc] = acc[m][n2][r] + bs;
            }
        }
}

// ---------------- block-local LSTM v4: split-k, fdot2, 8 waves ----------------
// 176 blocks x 512 thr; thread = (khalf = tid>>8, u = tid&255); 2 seqs per block.
__global__ __launch_bounds__(512)
void k_lstm4(const float* __restrict__ xg_q, const float* __restrict__ xg_d,
             const uint4* __restrict__ wpk_q, const uint4* __restrict__ wpk_d,
             float* __restrict__ enc_q, float* __restrict__ enc_d)
{
    __shared__ unsigned short h16[2][256];
    __shared__ float dots_l[2 * 256 * 9];   // stride 9: conflict-free
    const int tid = threadIdx.x;
    const int u = tid & 255, kh = tid >> 8;
    const int bid = blockIdx.x;
    const bool isq = bid >= 160;
    const int sg0 = isq ? (bid - 160) * 2 : bid * 2;
    const float* xg = isq ? xg_q : xg_d;
    const uint4* wpk = (isq ? wpk_q : wpk_d) + ((long)kh * 64 * 256 + u);
    float* enc = isq ? enc_q : enc_d;
    const int T = isq ? 16 : 128;
    float c0 = 0.f, c1 = 0.f;
    const unsigned int* h0p = (const unsigned int*)&h16[0][0] + kh * 64;
    const unsigned int* h1p = (const unsigned int*)&h16[1][0] + kh * 64;

    for (int t = 0; t < T; ++t) {
        // prefetch xg for this step (hidden under the dot loop)
        float xi0 = 0, xf0 = 0, xz0 = 0, xo0 = 0, xi1 = 0, xf1 = 0, xz1 = 0, xo1 = 0;
        if (tid < 256) {
            const float* x0 = xg + ((long)(sg0 + 0) * T + t) * 1024;
            const float* x1 = xg + ((long)(sg0 + 1) * T + t) * 1024;
            xi0 = x0[u]; xf0 = x0[u + 256]; xz0 = x0[u + 512]; xo0 = x0[u + 768];
            xi1 = x1[u]; xf1 = x1[u + 256]; xz1 = x1[u + 512]; xo1 = x1[u + 768];
        }
        float p0 = 0, p1 = 0, p2 = 0, p3 = 0, p4 = 0, p5 = 0, p6 = 0, p7 = 0;
        if (t > 0) {
            #pragma unroll 8
            for (int kp = 0; kp < 64; ++kp) {
                uint4 w = wpk[(long)kp * 256];
                h2t ha = u2h(h0p[kp]), hb = u2h(h1p[kp]);
                p0 = fdot2_(ha, u2h(w.x), p0); p1 = fdot2_(hb, u2h(w.x), p1);
                p2 = fdot2_(ha, u2h(w.y), p2); p3 = fdot2_(hb, u2h(w.y), p3);
                p4 = fdot2_(ha, u2h(w.z), p4); p5 = fdot2_(hb, u2h(w.z), p5);
                p6 = fdot2_(ha, u2h(w.w), p6); p7 = fdot2_(hb, u2h(w.w), p7);
            }
        }
        float* dl = &dots_l[(kh * 256 + u) * 9];
        dl[0] = p0; dl[1] = p1; dl[2] = p2; dl[3] = p3;
        dl[4] = p4; dl[5] = p5; dl[6] = p6; dl[7] = p7;
        __syncthreads();   // partials + (prev h reads) done
        if (tid < 256) {
            const float* d0 = &dots_l[u * 9];
            const float* d1 = &dots_l[(256 + u) * 9];
            float gi0 = xi0 + d0[0] + d1[0];
            float gi1 = xi1 + d0[1] + d1[1];
            float gf0 = xf0 + d0[2] + d1[2];
            float gf1 = xf1 + d0[3] + d1[3];
            float gz0 = xz0 + d0[4] + d1[4];
            float gz1 = xz1 + d0[5] + d1[5];
            float go0 = xo0 + d0[6] + d1[6];
            float go1 = xo1 + d0[7] + d1[7];
            c0 = sigmoidf_(gf0) * c0 + sigmoidf_(gi0) * tanhf(gz0);
            c1 = sigmoidf_(gf1) * c1 + sigmoidf_(gi1) * tanhf(gz1);
            float hn0 = sigmoidf_(go0) * tanhf(c0);
            float hn1 = sigmoidf_(go1) * tanhf(c1);
            h16[0][u] = f2h(hn0);
            h16[1][u] = f2h(hn1);
            enc[((long)(sg0 + 0) * T + t) * 256 + u] = hn0;
            enc[((long)(sg0 + 1) * T + t) * 256 + u] = hn1;
        }
        __syncthreads();   // h16 visible for next step
    }
}

// ---------------- build conv input xT fp16 [bd][q][d][64ic] ----------------
__global__ __launch_bounds__(256)
void k_build_xt(const float* __restrict__ pq, const float* __restrict__ pd,
                const int* __restrict__ qtok, const int* __restrict__ dtok,
                const float* __restrict__ alpha, unsigned short* __restrict__ xT)
{
    int p = blockIdx.x * 256 + threadIdx.x;
    if (p >= NBD * QL * DL) return;
    int d = p & 127, q = (p >> 7) & 15, bd = p >> 11;
    int b = bd / 10;
    const float* pqr = pq + ((long)b * 16 + q) * 50;
    const float* pdr = pd + ((long)bd * 128 + d) * 50;
    __attribute__((aligned(16))) unsigned short o[64];
    #pragma unroll
    for (int i = 0; i < 50; ++i) o[i] = f2h(pqr[i] * pdr[i]);
    o[50] = f2h(qtok[b * 16 + q] == dtok[bd * 128 + d] ? alpha[0] : 0.f);
    #pragma unroll
    for (int i = 51; i < 64; ++i) o[i] = 0;
    unsigned short* dst = xT + (long)p * 64;
    #pragma unroll
    for (int i = 0; i < 8; ++i) *(uint4*)(dst + i * 8) = *(const uint4*)(o + i * 8);
}

// ---------------- pack conv weights into swizzled A-fragment images ----------------
__global__ void k_pack_apk(const float* __restrict__ c1W, const float* __restrict__ c2W,
                           const float* __restrict__ c3W, unsigned short* __restrict__ Apk)
{
    int idx = blockIdx.x * 256 + threadIdx.x;
    if (idx >= 45 * 4096) return;
    int e = idx & 7, ci = (idx >> 3) & 7, row = (idx >> 6) & 15, mtl = (idx >> 10) & 3, s = idx >> 12;
    int k = ((ci ^ (row & 7)) << 3) + e;
    int ocl = mtl * 16 + row;
    float v = 0.f;
    if (ocl < 50 && k < 51) {
        if (s < 9)       { int sl = s;      v = c1W[((ocl * 51 + k) * 3 + sl / 3) * 3 + sl % 3]; }
        else if (s < 24) { int sl = s - 9;  v = c2W[((ocl * 51 + k) * 3 + sl / 5) * 5 + sl % 5]; }
        else             { int sl = s - 24; v = c3W[((ocl * 51 + k) * 3 + sl / 7) * 7 + sl % 7]; }
    }
    Apk[idx] = f2h(v);
}

// ---------------- pack 1x1 weights (transposed) + bias vector ----------------
__global__ void k_pack_cwb(const float* __restrict__ ccW,
                           const float* __restrict__ c1b, const float* __restrict__ c2b,
                           const float* __restrict__ c3b,
                           float* __restrict__ wccg, float* __restrict__ bvg)
{
    int idx = blockIdx.x * 256 + threadIdx.x;
    if (idx < 3840) {
        int oc = idx / 20, mf = idx % 20;
        int c = oc >> 6, ocl = oc & 63;
        wccg[idx] = (ocl < 50) ? ccW[mf * 150 + c * 50 + ocl] : 0.f;
    } else if (idx < 4032) {
        int oc = idx - 3840;
        int c = oc >> 6, ocl = oc & 63;
        const float* cb = (c == 0) ? c1b : (c == 1) ? c2b : c3b;
        bvg[oc] = (ocl < 50) ? cb[ocl] : 0.f;
    }
}

// ---------------- fused MFMA conv + relu + 1x1 + maxpool ----------------
#define WROWS 396   // 18 q-rows x 22 d-cols
template<int MTB, int KW>
__device__ __forceinline__ void conv_shift(
    const unsigned short* xw, const unsigned short* ab,
    f32x4 (&acc)[12][2], int lane, int wv, int dq, int dd)
{
    const int row = lane & 15, j0 = lane >> 4;
    f16x8 af[4][2];
    #pragma unroll
    for (int m = 0; m < 4; ++m)
        #pragma unroll
        for (int ks = 0; ks < 2; ++ks)
            af[m][ks] = *(const f16x8*)&ab[m * 1024 + row * 64 + (((j0 + 4 * ks) ^ (row & 7)) << 3)];
    const int dco = dd - (KW >> 1) + 3;
    #pragma unroll
    for (int nt = 0; nt < 2; ++nt) {
        int p0 = wv * 32 + nt * 16;
        int pos = ((p0 >> 4) + dq) * 22 + row + dco;
        f16x8 bf0 = *(const f16x8*)&xw[pos * 64 + ((j0 ^ (pos & 7)) << 3)];
        f16x8 bf1 = *(const f16x8*)&xw[pos * 64 + (((j0 + 4) ^ (pos & 7)) << 3)];
        #pragma unroll
        for (int m = 0; m < 4; ++m) {
            acc[MTB + m][nt] = __builtin_amdgcn_mfma_f32_16x16x32_f16(af[m][0], bf0, acc[MTB + m][nt], 0, 0, 0);
            acc[MTB + m][nt] = __builtin_amdgcn_mfma_f32_16x16x32_f16(af[m][1], bf1, acc[MTB + m][nt], 0, 0, 0);
        }
    }
}

__global__ __launch_bounds__(512)
void k_conv2(const unsigned short* __restrict__ xT, const unsigned short* __restrict__ Apk,
             const float* __restrict__ wccg, const float* __restrict__ bvg,
             float* __restrict__ pmax)
{
    __shared__ __align__(16) unsigned short smem_u[WROWS * 64 + 4096];
    __shared__ float bv_s[192];
    __shared__ float wmax_s[8 * 20];
    unsigned short* xw_u = smem_u;
    unsigned short* Ab_u = smem_u + WROWS * 64;
    float* wcc_s = (float*)smem_u;
    const int tid = threadIdx.x, lane = tid & 63, wv = tid >> 6;
    const int dqt = blockIdx.x, bd = blockIdx.y;
    const int D0 = dqt * 16;

    for (int i = tid; i < WROWS * 8; i += 512) {
        int row = i >> 3, ci = i & 7;
        int qa = row / 22 - 1, da = D0 - 3 + row % 22;
        int j = ci ^ (row & 7);
        uint4 v = make_uint4(0u, 0u, 0u, 0u);
        if (qa >= 0 && qa < 16 && da >= 0 && da < 128)
            v = *(const uint4*)&xT[((((long)bd * 16 + qa) * 128 + da) << 6) + j * 8];
        *(uint4*)&xw_u[row * 64 + ci * 8] = v;
    }
    if (tid < 192) bv_s[tid] = bvg[tid];

    uint4 areg = *(const uint4*)&Apk[tid * 8];
    f32x4 acc[12][2];
    #pragma unroll
    for (int mt = 0; mt < 12; ++mt) { acc[mt][0] = (f32x4)(0.f); acc[mt][1] = (f32x4)(0.f); }

    for (int s = 0; s < 45; ++s) {
        __syncthreads();
        *(uint4*)&Ab_u[tid * 8] = areg;
        if (s + 1 < 45) areg = *(const uint4*)&Apk[(s + 1) * 4096 + tid * 8];
        __syncthreads();
        if (s < 9)       { int sl = s;      conv_shift<0, 3>(xw_u, Ab_u, acc, lane, wv, sl / 3, sl % 3); }
        else if (s < 24) { int sl = s - 9;  conv_shift<4, 5>(xw_u, Ab_u, acc, lane, wv, sl / 5, sl % 5); }
        else             { int sl = s - 24; conv_shift<8, 7>(xw_u, Ab_u, acc, lane, wv, sl / 7, sl % 7); }
    }

    __syncthreads();
    for (int i = tid; i < 3840; i += 512) wcc_s[i] = wccg[i];

    #pragma unroll
    for (int mt = 0; mt < 12; ++mt)
        #pragma unroll
        for (int r = 0; r < 4; ++r) {
            float b = bv_s[mt * 16 + ((lane >> 4) << 2) + r];
            acc[mt][0][r] = fmaxf(acc[mt][0][r] + b, 0.f);
            acc[mt][1][r] = fmaxf(acc[mt][1][r] + b, 0.f);
        }
    __syncthreads();

    #pragma unroll 4
    for (int mf = 0; mf < 20; ++mf) {
        float g0 = 0.f, g1 = 0.f;
        #pragma unroll
        for (int mt = 0; mt < 12; ++mt)
            #pragma unroll
            for (int r = 0; r < 4; ++r) {
                float w = wcc_s[(mt * 16 + ((lane >> 4) << 2) + r) * 20 + mf];
                g0 = fmaf(acc[mt][0][r], w, g0);
                g1 = fmaf(acc[mt][1][r], w, g1);
            }
        g0 += __shfl_xor(g0, 16); g0 += __shfl_xor(g0, 32);
        g1 += __shfl_xor(g1, 16); g1 += __shfl_xor(g1, 32);
        float gm = fmaxf(g0, g1);
        gm = fmaxf(gm, __shfl_xor(gm, 1));
        gm = fmaxf(gm, __shfl_xor(gm, 2));
        gm = fmaxf(gm, __shfl_xor(gm, 4));
        gm = fmaxf(gm, __shfl_xor(gm, 8));
        if (lane == 0) wmax_s[wv * 20 + mf] = gm;
    }
    __syncthreads();
    if (tid < 20) {
        float m = wmax_s[tid];
        #pragma unroll
        for (int w = 1; w < 8; ++w) m = fmaxf(m, wmax_s[w * 20 + tid]);
        pmax[((long)bd * 8 + dqt) * 20 + tid] = m;
    }
}

// ---------------- finalize: max over 8 d-eighths, +ccb, dot outW ----------------
__global__ void k_finalize(const float* __restrict__ pmax, const float* __restrict__ ccb,
                           const float* __restrict__ outW, const float* __restrict__ outb,
                           float* __restrict__ out)
{
    int bd = blockIdx.x;
    int t = threadIdx.x;  // 64
    float v = 0.f;
    if (t < 20) {
        const float* p = pmax + (long)bd * 160;
        float m = p[t];
        #pragma unroll
        for (int i = 1; i < 8; ++i) m = fmaxf(m, p[i * 20 + t]);
        v = (m + ccb[t]) * outW[t];
    }
    for (int off = 32; off; off >>= 1) v += __shfl_xor(v, off);
    if (t == 0) out[bd] = v + outb[0];
}

extern "C" void kernel_launch(void* const* d_in, const int* in_sizes, int n_in,
                              void* d_out, int out_size, void* d_ws, size_t ws_size,
                              hipStream_t stream)
{
    const int*   q_tok  = (const int*)d_in[0];
    const int*   d_tok  = (const int*)d_in[1];
    const float* emb    = (const float*)d_in[4];
    const float* proj_W = (const float*)d_in[5];
    const float* proj_b = (const float*)d_in[6];
    const float* q_Wih  = (const float*)d_in[7];
    const float* q_Whh  = (const float*)d_in[8];
    const float* q_bih  = (const float*)d_in[9];
    const float* q_bhh  = (const float*)d_in[10];
    const float* d_Wih  = (const float*)d_in[11];
    const float* d_Whh  = (const float*)d_in[12];
    const float* d_bih  = (const float*)d_in[13];
    const float* d_bhh  = (const float*)d_in[14];
    const float* qp_W   = (const float*)d_in[15];
    const float* qp_b   = (const float*)d_in[16];
    const float* dp_W   = (const float*)d_in[17];
    const float* dp_b   = (const float*)d_in[18];
    const float* alpha  = (const float*)d_in[19];
    const float* c1W = (const float*)d_in[20]; const float* c1b = (const float*)d_in[21];
    const float* c2W = (const float*)d_in[22]; const float* c2b = (const float*)d_in[23];
    const float* c3W = (const float*)d_in[24]; const float* c3b = (const float*)d_in[25];
    const float* ccW = (const float*)d_in[26]; const float* ccb = (const float*)d_in[27];
    const float* outW = (const float*)d_in[28]; const float* outb = (const float*)d_in[29];
    float* out = (float*)d_out;

    float* ws = (float*)d_ws;
    size_t o = 0;
    auto alloc = [&](size_t n) { float* p = ws + o; o += (n + 63) & ~(size_t)63; return p; };
    float* WihT_q = alloc(300 * 1024);
    float* WihT_d = alloc(300 * 1024);
    float* Wcq    = alloc(300 * 1024);
    float* Wcd    = alloc(300 * 1024);
    float* bq     = alloc(1024);
    float* bdv    = alloc(1024);
    unsigned int* wpkq = (unsigned int*)alloc(131072);       // 512 KB
    unsigned int* wpkd = (unsigned int*)alloc(131072);
    unsigned short* WcTq16 = (unsigned short*)alloc(163840); // 1024*320 fp16
    unsigned short* WcTd16 = (unsigned short*)alloc(163840);
    float* enc_q  = alloc(512 * 256);
    float* pq     = alloc(512 * 50);
    float* pd     = alloc((size_t)40960 * 50);
    unsigned short* Apk  = (unsigned short*)alloc(92160);
    float* wccg   = alloc(3840);
    float* bvg    = alloc(192);
    float* pmax   = alloc((size_t)320 * 8 * 20);
    float* enc_d  = alloc((size_t)40960 * 256);
    float* xg_q   = alloc((size_t)512 * 1024);
    float* xg_d   = alloc((size_t)40960 * 1024);
    unsigned short* xT    = (unsigned short*)xg_d;   // alias: xg_d dead after LSTM
    unsigned short* emb16 = (unsigned short*)enc_d;  // alias: emb16 dead before LSTM writes enc_d

    // 1. transpose Wih
    k_transpose_wih<<<1200, 256, 0, stream>>>(q_Wih, WihT_q);
    k_transpose_wih<<<1200, 256, 0, stream>>>(d_Wih, WihT_d);
    // 2. W_comb = proj_W @ WihT (fp32, tiny)
    k_gemm<false><<<dim3(16, 5), 256, 0, stream>>>(300, 1024, 300, proj_W, 300,
        (const int*)nullptr, WihT_q, 1024, (const float*)nullptr, Wcq, 1024);
    k_gemm<false><<<dim3(16, 5), 256, 0, stream>>>(300, 1024, 300, proj_W, 300,
        (const int*)nullptr, WihT_d, 1024, (const float*)nullptr, Wcd, 1024);
    // 3. bias_comb
    k_bias<<<4, 256, 0, stream>>>(WihT_q, proj_b, q_bih, q_bhh, bq);
    k_bias<<<4, 256, 0, stream>>>(WihT_d, proj_b, d_bih, d_bhh, bdv);
    // 4. pack LSTM weights (fp16 pairs, gate-interleaved dwordx4)
    k_pack_whh4<<<512, 256, 0, stream>>>(q_Whh, wpkq);
    k_pack_whh4<<<512, 256, 0, stream>>>(d_Whh, wpkd);
    // 5. fp16 packs for the MFMA gather-GEMM
    k_pack_emb16<<<62500, 256, 0, stream>>>(emb, emb16);
    k_pack_wct16<<<1280, 256, 0, stream>>>(Wcq, WcTq16);
    k_pack_wct16<<<1280, 256, 0, stream>>>(Wcd, WcTd16);
    // 6. conv weight packs
    k_pack_apk<<<720, 256, 0, stream>>>(c1W, c2W, c3W, Apk);
    k_pack_cwb<<<16, 256, 0, stream>>>(ccW, c1b, c2b, c3b, wccg, bvg);
    // 7. xg = emb16[tok] @ WcT + bias (MFMA fp16)
    k_gemm16<true><<<dim3(8, 8), 256, 0, stream>>>(emb16, q_tok, WcTq16, bq, xg_q);
    k_gemm16<true><<<dim3(8, 640), 256, 0, stream>>>(emb16, d_tok, WcTd16, bdv, xg_d);
    // 8. LSTMs: block-local, split-k, fdot2
    k_lstm4<<<176, 512, 0, stream>>>(xg_q, xg_d, (const uint4*)wpkq, (const uint4*)wpkd,
                                     enc_q, enc_d);
    // 9. pq / pd projections (fp32)
    k_gemm<false><<<dim3(1, 8), 256, 0, stream>>>(512, 50, 256, enc_q, 256,
        (const int*)nullptr, qp_W, 50, qp_b, pq, 50);
    k_gemm<false><<<dim3(1, 640), 256, 0, stream>>>(40960, 50, 256, enc_d, 256,
        (const int*)nullptr, dp_W, 50, dp_b, pd, 50);
    // 10. build fp16 conv input
    k_build_xt<<<2560, 256, 0, stream>>>(pq, pd, q_tok, d_tok, alpha, xT);
    // 11. fused MFMA convs + relu + 1x1 + maxpool partials
    k_conv2<<<dim3(8, 320), 512, 0, stream>>>(xT, Apk, wccg, bvg, pmax);
    // 12. finalize scores
    k_finalize<<<320, 64, 0, stream>>>(pmax, ccb, outW, outb, out);
}